// Round 7
// baseline (2551.521 us; speedup 1.0000x reference)
//
#include <hip/hip_runtime.h>
#include <hip/hip_bf16.h>

#define D_ 128
#define GRID_P 256   // persistent blocks = 1 per CU

typedef __attribute__((ext_vector_type(8))) short short8;
typedef __attribute__((ext_vector_type(4))) float f32x4;
typedef __attribute__((address_space(1))) const unsigned int g_u32;
typedef __attribute__((address_space(3))) unsigned int l_u32;

static __device__ __forceinline__ float lrelu(float x) { return x > 0.f ? x : 0.01f * x; }
static __device__ __forceinline__ short f2bf(float f) {
    __hip_bfloat16 h = __float2bfloat16(f);
    return *reinterpret_cast<short*>(&h);
}
static __device__ __forceinline__ unsigned short f2bfu(float f) {
    __hip_bfloat16 h = __float2bfloat16(f);
    return *reinterpret_cast<unsigned short*>(&h);
}

// ---------------- prep: weights f32->bf16 transposed+combined, nodes/glbs -> bf16 ----------------
__global__ void prep(const float* __restrict__ Wn0, const float* __restrict__ We0,
                     const float* __restrict__ Wn1, const float* __restrict__ We1,
                     const float* __restrict__ bn0, const float* __restrict__ be0,
                     const float* __restrict__ bn1, const float* __restrict__ be1,
                     const float* __restrict__ nodes, const float* __restrict__ glbs,
                     long nq,
                     short* __restrict__ W0T, short* __restrict__ W1T,
                     float* __restrict__ b0c, float* __restrict__ b1c,
                     unsigned short* __restrict__ nodes_bf, unsigned short* __restrict__ glbs_bf) {
    long i = (long)blockIdx.x * 256 + threadIdx.x;
    if (i < nq) {
        float4 v = ((const float4*)nodes)[i];
        short4 o;
        o.x = f2bf(v.x); o.y = f2bf(v.y); o.z = f2bf(v.z); o.w = f2bf(v.w);
        ((short4*)nodes_bf)[i] = o;
        return;
    }
    long j = i - nq;
    if (j < 512 * 512) {
        int n = (int)(j >> 9), k = (int)(j & 511);
        float v = (n < 256) ? Wn0[k * 256 + n] : We0[k * 256 + (n - 256)];
        W0T[j] = f2bf(v);
        return;
    }
    j -= 512 * 512;
    if (j < 256 * 256) {
        int n = (int)(j >> 8), k = (int)(j & 255);
        float v = (n < 128) ? Wn1[k * 128 + n] : We1[k * 128 + (n - 128)];
        W1T[j] = f2bf(v);
        return;
    }
    j -= 256 * 256;
    if (j < 512) { b0c[j] = (j < 256) ? bn0[j] : be0[j - 256]; return; }
    if (j < 768) { int t = (int)j - 512; b1c[t] = (t < 128) ? bn1[t] : be1[t - 128]; return; }
    j -= 768;
    if (j < 1024) glbs_bf[j] = f2bfu(glbs[j]);
}

// ---------------- counting sort of edges by receiver ----------------
__global__ void hist_recv(const int* __restrict__ receivers, int E_, int* __restrict__ cnt) {
    int e = blockIdx.x * 256 + threadIdx.x;
    if (e < E_) atomicAdd(&cnt[receivers[e]], 1);
}

__global__ void scan_counts(const int* __restrict__ cnt, int N_, int* __restrict__ off) {
    __shared__ int part[256];
    int t = threadIdx.x;
    int chunk = (N_ + 255) / 256;
    int b = t * chunk, e = min(N_, b + chunk);
    int s = 0;
    for (int i = b; i < e; i++) s += cnt[i];
    part[t] = s;
    __syncthreads();
    for (int o = 1; o < 256; o <<= 1) {
        int v = (t >= o) ? part[t - o] : 0;
        __syncthreads();
        part[t] += v;
        __syncthreads();
    }
    int run = part[t] - s;
    for (int i = b; i < e; i++) { off[i] = run; run += cnt[i]; }
}

__global__ void place_edges(const int* __restrict__ receivers, int E_,
                            int* __restrict__ off, int* __restrict__ sorted) {
    int e = blockIdx.x * 256 + threadIdx.x;
    if (e < E_) {
        int p = atomicAdd(&off[receivers[e]], 1);
        sorted[p] = e;
    }
}

// ---------------- per-graph segment sums ----------------
__global__ void seg_sum(const float* __restrict__ src, const int* __restrict__ counts,
                        int G, int rows, int chunk, float* __restrict__ out) {
    int c4 = threadIdx.x & 31;
    int rl = threadIdx.x >> 5;
    int r0 = blockIdx.x * chunk + rl;
    int rend = min(rows, blockIdx.x * chunk + chunk);
    int s_ = 0;
    int cu0 = 0x7fffffff, cu1 = 0x7fffffff, cu2 = 0x7fffffff, cu3 = 0x7fffffff;
    int cu4 = 0x7fffffff, cu5 = 0x7fffffff, cu6 = 0x7fffffff, cu7 = 0x7fffffff;
#define CUF(I, CU) if (I < G) { s_ += counts[I]; CU = s_; }
    CUF(0, cu0) CUF(1, cu1) CUF(2, cu2) CUF(3, cu3)
    CUF(4, cu4) CUF(5, cu5) CUF(6, cu6) CUF(7, cu7)
#undef CUF
    f32x4 acc = {0.f, 0.f, 0.f, 0.f};
    int accg = -1;
    for (int r = r0; r < rend; r += 8) {
        int g = (r >= cu0) + (r >= cu1) + (r >= cu2) + (r >= cu3)
              + (r >= cu4) + (r >= cu5) + (r >= cu6) + (r >= cu7);
        if (g != accg) {
            if (accg >= 0) {
#pragma unroll
                for (int j = 0; j < 4; j++) atomicAdd(&out[accg * D_ + c4 * 4 + j], acc[j]);
            }
            acc = (f32x4){0.f, 0.f, 0.f, 0.f}; accg = g;
        }
        const float4 v = *(const float4*)(src + (long)r * D_ + c4 * 4);
        acc[0] += v.x; acc[1] += v.y; acc[2] += v.z; acc[3] += v.w;
    }
    if (accg >= 0) {
#pragma unroll
        for (int j = 0; j < 4; j++) atomicAdd(&out[accg * D_ + c4 * 4 + j], acc[j]);
    }
}

// ---------------- global-feature MLP ----------------
__global__ void global_mlp(const float* __restrict__ glbs, const float* __restrict__ sumn,
                           const float* __restrict__ sume,
                           const float* __restrict__ Wg, const float* __restrict__ bg,
                           const float* __restrict__ Wgn, const float* __restrict__ bgn,
                           const float* __restrict__ Wge, const float* __restrict__ bge,
                           const float* __restrict__ Wf, const float* __restrict__ bfv,
                           float* __restrict__ outg) {
    __shared__ float s_tmp[384];
    int r = blockIdx.x;
    int c = threadIdx.x;
    float a0 = 0.f, a1 = 0.f, a2 = 0.f;
    for (int k = 0; k < 128; k++) {
        a0 += glbs[r * 128 + k] * Wg[k * 128 + c];
        a1 += sumn[r * 128 + k] * Wgn[k * 128 + c];
        a2 += sume[r * 128 + k] * Wge[k * 128 + c];
    }
    s_tmp[c]       = lrelu(a0 + bg[c]);
    s_tmp[128 + c] = lrelu(a1 + bgn[c]);
    s_tmp[256 + c] = lrelu(a2 + bge[c]);
    __syncthreads();
    float a = 0.f;
    for (int k = 0; k < 384; k++) a += s_tmp[k] * Wf[k * 128 + c];
    outg[r * 128 + c] = lrelu(a + bfv[c]);
}

// ---------------- persistent fused per-edge MLP (R4 block code, contiguous tile chunks) ----------------
// 256 blocks x 512 threads = 8 waves (2M x 4N). Each block owns a CONTIGUOUS range of
// 128-edge tiles of the receiver-sorted order. Block body identical to R4.
__launch_bounds__(512, 2)
__global__ void edge_mlp_persist(const unsigned short* __restrict__ nodes_bf,
                                 const float* __restrict__ edges,
                                 const unsigned short* __restrict__ glbs_bf,
                                 const int* __restrict__ senders, const int* __restrict__ receivers,
                                 const int* __restrict__ sorted_eid,
                                 const int* __restrict__ n_edge, int G, int NT,
                                 const short* __restrict__ W0T, const short* __restrict__ W1T,
                                 const float* __restrict__ b0c, const float* __restrict__ b1c,
                                 float* __restrict__ out_nodes, float* __restrict__ out_edges) {
    __shared__ __align__(16) char sX[128 * 1024];
    __shared__ int s_eid[128], s_snd[128], s_recv[128], s_gid[128];

    const int tid  = threadIdx.x;
    const int lane = tid & 63;
    const int wid  = tid >> 6;
    const int wm   = wid >> 2;
    const int wn   = wid & 3;
    const int l15  = lane & 15;
    const int lk   = lane >> 4;

    // cumulative edge counts (graph id by ORIGINAL edge index), G <= 8
    int s_ = 0;
    int cu0 = 0x7fffffff, cu1 = 0x7fffffff, cu2 = 0x7fffffff, cu3 = 0x7fffffff;
    int cu4 = 0x7fffffff, cu5 = 0x7fffffff, cu6 = 0x7fffffff, cu7 = 0x7fffffff;
#define CUF(I, CU) if (I < G) { s_ += n_edge[I]; CU = s_; }
    CUF(0, cu0) CUF(1, cu1) CUF(2, cu2) CUF(3, cu3)
    CUF(4, cu4) CUF(5, cu5) CUF(6, cu6) CUF(7, cu7)
#undef CUF

    // contiguous tile partition: first `rem` blocks get per+1 tiles
    const int per = NT / GRID_P;
    const int rem = NT - per * GRID_P;
    const int bid = blockIdx.x;
    const int t0  = bid * per + min(bid, rem);
    const int t1  = t0 + per + (bid < rem ? 1 : 0);

    for (int tile = t0; tile < t1; ++tile) {
        const int base = tile * 128;

        if (tid < 128) {
            int eid = sorted_eid[base + tid];
            s_eid[tid]  = eid;
            s_snd[tid]  = senders[eid];
            s_recv[tid] = receivers[eid];
            s_gid[tid]  = (eid >= cu0) + (eid >= cu1) + (eid >= cu2) + (eid >= cu3)
                        + (eid >= cu4) + (eid >= cu5) + (eid >= cu6) + (eid >= cu7);
        }
        __syncthreads();

        // ---- stage X into LDS (each wave stages one row per round) ----
#pragma unroll
        for (int r = 0; r < 16; ++r) {
            const int e   = r * 8 + wid;    // wave-uniform row
            const int eid = s_eid[e];
            const int snd = s_snd[e];
            const int rcv = s_recv[e];
            const int g   = s_gid[e];
            char* dst = sX + e * 1024;      // linear dst; HW adds lane*16
            if (lk == 2) {
                // edges are f32: load+convert+swizzled ds_write
                const float* fp = edges + (long)eid * 128 + l15 * 8;
                float4 v0 = *(const float4*)fp;
                float4 v1 = *(const float4*)(fp + 4);
                short8 a;
                a[0] = f2bf(v0.x); a[1] = f2bf(v0.y); a[2] = f2bf(v0.z); a[3] = f2bf(v0.w);
                a[4] = f2bf(v1.x); a[5] = f2bf(v1.y); a[6] = f2bf(v1.z); a[7] = f2bf(v1.w);
                *(short8*)(sX + e * 1024 + ((lane * 16) ^ ((e & 7) << 4))) = a;
            } else {
                // bf16 sources: glds, source pre-swizzled
                const int w = l15 ^ (e & 7);
                const unsigned short* bp = (lk == 0) ? nodes_bf + (long)snd * 128
                                         : (lk == 1) ? nodes_bf + (long)rcv * 128
                                                     : glbs_bf + (long)g * 128;
                __builtin_amdgcn_global_load_lds((g_u32*)(bp + w * 8), (l_u32*)dst, 16, 0, 0);
            }
        }
        __syncthreads();

        // ---- layer 1: X[128x512] @ W0c[512x512] ----
        f32x4 acc[4][8];
#pragma unroll
        for (int mt = 0; mt < 4; ++mt)
#pragma unroll
            for (int nt = 0; nt < 8; ++nt) acc[mt][nt] = (f32x4){0.f, 0.f, 0.f, 0.f};

#pragma unroll
        for (int t = 0; t < 16; ++t) {
            short8 bfr[8];
#pragma unroll
            for (int nt = 0; nt < 8; ++nt) {
                int n = wn * 128 + nt * 16 + l15;
                bfr[nt] = *(const short8*)(W0T + (long)n * 512 + t * 32 + lk * 8);
            }
#pragma unroll
            for (int mt = 0; mt < 4; ++mt) {
                int row = wm * 64 + mt * 16 + l15;
                short8 af = *(const short8*)(sX + row * 1024 + ((t * 64 + lk * 16) ^ ((row & 7) << 4)));
#pragma unroll
                for (int nt = 0; nt < 8; ++nt)
                    acc[mt][nt] = __builtin_amdgcn_mfma_f32_16x16x32_bf16(af, bfr[nt], acc[mt][nt], 0, 0, 0);
            }
        }
        __syncthreads();

        // bias + leaky + bf16 -> LDS H (same geometry/swizzle as X)
#pragma unroll
        for (int nt = 0; nt < 8; ++nt) {
            int col = wn * 128 + nt * 16 + l15;
            float bias = b0c[col];
#pragma unroll
            for (int mt = 0; mt < 4; ++mt) {
#pragma unroll
                for (int q = 0; q < 4; ++q) {
                    int row = wm * 64 + mt * 16 + lk * 4 + q;
                    float v = lrelu(acc[mt][nt][q] + bias);
                    *(short*)(sX + row * 1024 + ((col * 2) ^ ((row & 7) << 4))) = f2bf(v);
                }
            }
        }
        __syncthreads();

        // ---- layer 2 ----
        const int branch = wn >> 1;
        const int halfn  = wn & 1;
        f32x4 acc2[4][4];
#pragma unroll
        for (int mt = 0; mt < 4; ++mt)
#pragma unroll
            for (int nt = 0; nt < 4; ++nt) acc2[mt][nt] = (f32x4){0.f, 0.f, 0.f, 0.f};

#pragma unroll
        for (int kt = 0; kt < 8; ++kt) {
            short8 bfr2[4];
#pragma unroll
            for (int nt = 0; nt < 4; ++nt) {
                int ncl = halfn * 64 + nt * 16 + l15;
                bfr2[nt] = *(const short8*)(W1T + (long)(branch * 128 + ncl) * 256 + kt * 32 + lk * 8);
            }
#pragma unroll
            for (int mt = 0; mt < 4; ++mt) {
                int row = wm * 64 + mt * 16 + l15;
                int kbyte = (branch * 256 + kt * 32 + lk * 8) * 2;
                short8 af = *(const short8*)(sX + row * 1024 + (kbyte ^ ((row & 7) << 4)));
#pragma unroll
                for (int nt = 0; nt < 4; ++nt)
                    acc2[mt][nt] = __builtin_amdgcn_mfma_f32_16x16x32_bf16(af, bfr2[nt], acc2[mt][nt], 0, 0, 0);
            }
        }
        __syncthreads();  // H reads done; reuse sX as f32 msg buffer

        // epilogue: msgs -> LDS (swizzled), edge-updates -> global
#pragma unroll
        for (int nt = 0; nt < 4; ++nt) {
            int ncl = halfn * 64 + nt * 16 + l15;
            float bias = b1c[branch * 128 + ncl];
#pragma unroll
            for (int mt = 0; mt < 4; ++mt) {
#pragma unroll
                for (int q = 0; q < 4; ++q) {
                    int row = wm * 64 + mt * 16 + lk * 4 + q;
                    float v = lrelu(acc2[mt][nt][q] + bias);
                    if (branch == 0) {
                        *(float*)(sX + row * 512 + ((ncl * 4) ^ (((row >> 2) & 3) << 6))) = v;
                    } else {
                        out_edges[(long)s_eid[row] * D_ + ncl] = v;
                    }
                }
            }
        }
        __syncthreads();

        // segmented reduction over sorted receivers: one atomic per (segment x col)
        {
            int c  = tid & 127;
            int qr = tid >> 7;        // rows [qr*32, qr*32+32)
            int r0 = qr * 32, r1 = r0 + 32;
            float acc_s = 0.f;
            int cur = s_recv[r0];
            for (int r = r0; r < r1; ++r) {
                int rc = s_recv[r];
                if (rc != cur) {
                    atomicAdd(&out_nodes[(long)cur * D_ + c], acc_s);
                    acc_s = 0.f; cur = rc;
                }
                acc_s += *(const float*)(sX + r * 512 + ((c * 4) ^ (((r >> 2) & 3) << 6)));
            }
            atomicAdd(&out_nodes[(long)cur * D_ + c], acc_s);
        }
        __syncthreads();  // reduce reads done before next tile's meta/stage overwrite
    }
}

extern "C" void kernel_launch(void* const* d_in, const int* in_sizes, int n_in,
                              void* d_out, int out_size, void* d_ws, size_t ws_size,
                              hipStream_t stream) {
    const float* nodes     = (const float*)d_in[0];
    const float* edges     = (const float*)d_in[1];
    const float* glbs      = (const float*)d_in[2];
    const int*   senders   = (const int*)d_in[3];
    const int*   receivers = (const int*)d_in[4];
    const int*   n_node    = (const int*)d_in[5];
    const int*   n_edge    = (const int*)d_in[6];
    const float* Wn0 = (const float*)d_in[7];
    const float* bn0 = (const float*)d_in[8];
    const float* Wn1 = (const float*)d_in[9];
    const float* bn1 = (const float*)d_in[10];
    const float* We0 = (const float*)d_in[11];
    const float* be0 = (const float*)d_in[12];
    const float* We1 = (const float*)d_in[13];
    const float* be1 = (const float*)d_in[14];
    const float* Wgn = (const float*)d_in[15];
    const float* bgn = (const float*)d_in[16];
    const float* Wge = (const float*)d_in[17];
    const float* bge = (const float*)d_in[18];
    const float* Wg  = (const float*)d_in[19];
    const float* bg  = (const float*)d_in[20];
    const float* Wf  = (const float*)d_in[21];
    const float* bfv = (const float*)d_in[22];

    const int N = in_sizes[0] / 128;
    const int E = in_sizes[1] / 128;
    const int G = in_sizes[2] / 128;
    const int NT = E / 128;

    char*  ws   = (char*)d_ws;
    short* W0T  = (short*)(ws);                      // 524288 B
    short* W1T  = (short*)(ws + 524288);             // 131072 B
    float* b0c  = (float*)(ws + 655360);             // 2048 B
    float* b1c  = (float*)(ws + 657408);             // 1024 B
    float* sumn = (float*)(ws + 658432);             // 4096 B
    float* sume = (float*)(ws + 662528);             // 4096 B
    unsigned short* glbs_bf  = (unsigned short*)(ws + 666624);   // 2048 B
    unsigned short* nodes_bf = (unsigned short*)(ws + 669696);   // N*256 B
    char*  ws2  = ws + 669696 + (size_t)N * 256;
    int* cnt        = (int*)(ws2);                   // N*4
    int* tmp_off    = (int*)(ws2 + (size_t)N * 4);   // N*4
    int* sorted_eid = (int*)(ws2 + (size_t)N * 8);   // E*4

    float* out_nodes = (float*)d_out;
    float* out_edges = out_nodes + (long)N * 128;
    float* out_glb   = out_edges + (long)E * 128;

    hipMemsetAsync(out_nodes, 0, (size_t)N * 128 * sizeof(float), stream);
    hipMemsetAsync(sumn, 0, 8192, stream);
    hipMemsetAsync(cnt, 0, (size_t)N * 4, stream);

    const long nq = (long)N * 32;
    const long prep_items = nq + 512 * 512 + 256 * 256 + 768 + 1024;
    prep<<<(int)((prep_items + 255) / 256), 256, 0, stream>>>(
        Wn0, We0, Wn1, We1, bn0, be0, bn1, be1, nodes, glbs, nq,
        W0T, W1T, b0c, b1c, nodes_bf, glbs_bf);

    hist_recv<<<(E + 255) / 256, 256, 0, stream>>>(receivers, E, cnt);
    scan_counts<<<1, 256, 0, stream>>>(cnt, N, tmp_off);
    place_edges<<<(E + 255) / 256, 256, 0, stream>>>(receivers, E, tmp_off, sorted_eid);

    edge_mlp_persist<<<GRID_P, 512, 0, stream>>>(nodes_bf, edges, glbs_bf, senders, receivers,
                                                 sorted_eid, n_edge, G, NT,
                                                 W0T, W1T, b0c, b1c, out_nodes, out_edges);

    seg_sum<<<(N + 127) / 128, 256, 0, stream>>>(nodes, n_node, G, N, 128, sumn);
    seg_sum<<<(E + 255) / 256, 256, 0, stream>>>(edges, n_edge, G, E, 256, sume);

    global_mlp<<<G, 128, 0, stream>>>(glbs, sumn, sume, Wg, bg, Wgn, bgn, Wge, bge, Wf, bfv,
                                      out_glb);
}

// Round 8
// 2535.873 us; speedup vs baseline: 1.0062x; 1.0062x over previous
//
#include <hip/hip_runtime.h>
#include <hip/hip_bf16.h>

#define D_ 128
#define GRID_P 256   // persistent blocks = 1 per CU

typedef __attribute__((ext_vector_type(8))) short short8;
typedef __attribute__((ext_vector_type(4))) float f32x4;
typedef __attribute__((address_space(1))) const unsigned int g_u32;
typedef __attribute__((address_space(3))) unsigned int l_u32;

static __device__ __forceinline__ float lrelu(float x) { return x > 0.f ? x : 0.01f * x; }
static __device__ __forceinline__ short f2bf(float f) {
    __hip_bfloat16 h = __float2bfloat16(f);
    return *reinterpret_cast<short*>(&h);
}
static __device__ __forceinline__ unsigned short f2bfu(float f) {
    __hip_bfloat16 h = __float2bfloat16(f);
    return *reinterpret_cast<unsigned short*>(&h);
}

// ---------------- prep: weights f32->bf16 transposed+combined, nodes/glbs -> bf16 ----------------
__global__ void prep(const float* __restrict__ Wn0, const float* __restrict__ We0,
                     const float* __restrict__ Wn1, const float* __restrict__ We1,
                     const float* __restrict__ bn0, const float* __restrict__ be0,
                     const float* __restrict__ bn1, const float* __restrict__ be1,
                     const float* __restrict__ nodes, const float* __restrict__ glbs,
                     long nq,
                     short* __restrict__ W0T, short* __restrict__ W1T,
                     float* __restrict__ b0c, float* __restrict__ b1c,
                     unsigned short* __restrict__ nodes_bf, unsigned short* __restrict__ glbs_bf) {
    long i = (long)blockIdx.x * 256 + threadIdx.x;
    if (i < nq) {
        f32x4 v = __builtin_nontemporal_load((const f32x4*)nodes + i);
        short4 o;
        o.x = f2bf(v[0]); o.y = f2bf(v[1]); o.z = f2bf(v[2]); o.w = f2bf(v[3]);
        ((short4*)nodes_bf)[i] = o;
        return;
    }
    long j = i - nq;
    if (j < 512 * 512) {
        int n = (int)(j >> 9), k = (int)(j & 511);
        float v = (n < 256) ? Wn0[k * 256 + n] : We0[k * 256 + (n - 256)];
        W0T[j] = f2bf(v);
        return;
    }
    j -= 512 * 512;
    if (j < 256 * 256) {
        int n = (int)(j >> 8), k = (int)(j & 255);
        float v = (n < 128) ? Wn1[k * 128 + n] : We1[k * 128 + (n - 128)];
        W1T[j] = f2bf(v);
        return;
    }
    j -= 256 * 256;
    if (j < 512) { b0c[j] = (j < 256) ? bn0[j] : be0[j - 256]; return; }
    if (j < 768) { int t = (int)j - 512; b1c[t] = (t < 128) ? bn1[t] : be1[t - 128]; return; }
    j -= 768;
    if (j < 1024) glbs_bf[j] = f2bfu(glbs[j]);
}

// ---------------- counting sort of edges by receiver ----------------
__global__ void hist_recv(const int* __restrict__ receivers, int E_, int* __restrict__ cnt) {
    int e = blockIdx.x * 256 + threadIdx.x;
    if (e < E_) atomicAdd(&cnt[receivers[e]], 1);
}

__global__ void scan_counts(const int* __restrict__ cnt, int N_, int* __restrict__ off) {
    __shared__ int part[256];
    int t = threadIdx.x;
    int chunk = (N_ + 255) / 256;
    int b = t * chunk, e = min(N_, b + chunk);
    int s = 0;
    for (int i = b; i < e; i++) s += cnt[i];
    part[t] = s;
    __syncthreads();
    for (int o = 1; o < 256; o <<= 1) {
        int v = (t >= o) ? part[t - o] : 0;
        __syncthreads();
        part[t] += v;
        __syncthreads();
    }
    int run = part[t] - s;
    for (int i = b; i < e; i++) { off[i] = run; run += cnt[i]; }
}

__global__ void place_edges(const int* __restrict__ receivers, int E_,
                            int* __restrict__ off, int* __restrict__ sorted) {
    int e = blockIdx.x * 256 + threadIdx.x;
    if (e < E_) {
        int p = atomicAdd(&off[receivers[e]], 1);
        sorted[p] = e;
    }
}

// ---------------- per-graph segment sums ----------------
__global__ void seg_sum(const float* __restrict__ src, const int* __restrict__ counts,
                        int G, int rows, int chunk, float* __restrict__ out) {
    int c4 = threadIdx.x & 31;
    int rl = threadIdx.x >> 5;
    int r0 = blockIdx.x * chunk + rl;
    int rend = min(rows, blockIdx.x * chunk + chunk);
    int s_ = 0;
    int cu0 = 0x7fffffff, cu1 = 0x7fffffff, cu2 = 0x7fffffff, cu3 = 0x7fffffff;
    int cu4 = 0x7fffffff, cu5 = 0x7fffffff, cu6 = 0x7fffffff, cu7 = 0x7fffffff;
#define CUF(I, CU) if (I < G) { s_ += counts[I]; CU = s_; }
    CUF(0, cu0) CUF(1, cu1) CUF(2, cu2) CUF(3, cu3)
    CUF(4, cu4) CUF(5, cu5) CUF(6, cu6) CUF(7, cu7)
#undef CUF
    f32x4 acc = {0.f, 0.f, 0.f, 0.f};
    int accg = -1;
    for (int r = r0; r < rend; r += 8) {
        int g = (r >= cu0) + (r >= cu1) + (r >= cu2) + (r >= cu3)
              + (r >= cu4) + (r >= cu5) + (r >= cu6) + (r >= cu7);
        if (g != accg) {
            if (accg >= 0) {
#pragma unroll
                for (int j = 0; j < 4; j++) atomicAdd(&out[accg * D_ + c4 * 4 + j], acc[j]);
            }
            acc = (f32x4){0.f, 0.f, 0.f, 0.f}; accg = g;
        }
        const f32x4 v = __builtin_nontemporal_load((const f32x4*)(src + (long)r * D_) + c4);
        acc[0] += v[0]; acc[1] += v[1]; acc[2] += v[2]; acc[3] += v[3];
    }
    if (accg >= 0) {
#pragma unroll
        for (int j = 0; j < 4; j++) atomicAdd(&out[accg * D_ + c4 * 4 + j], acc[j]);
    }
}

// ---------------- global-feature MLP ----------------
__global__ void global_mlp(const float* __restrict__ glbs, const float* __restrict__ sumn,
                           const float* __restrict__ sume,
                           const float* __restrict__ Wg, const float* __restrict__ bg,
                           const float* __restrict__ Wgn, const float* __restrict__ bgn,
                           const float* __restrict__ Wge, const float* __restrict__ bge,
                           const float* __restrict__ Wf, const float* __restrict__ bfv,
                           float* __restrict__ outg) {
    __shared__ float s_tmp[384];
    int r = blockIdx.x;
    int c = threadIdx.x;
    float a0 = 0.f, a1 = 0.f, a2 = 0.f;
    for (int k = 0; k < 128; k++) {
        a0 += glbs[r * 128 + k] * Wg[k * 128 + c];
        a1 += sumn[r * 128 + k] * Wgn[k * 128 + c];
        a2 += sume[r * 128 + k] * Wge[k * 128 + c];
    }
    s_tmp[c]       = lrelu(a0 + bg[c]);
    s_tmp[128 + c] = lrelu(a1 + bgn[c]);
    s_tmp[256 + c] = lrelu(a2 + bge[c]);
    __syncthreads();
    float a = 0.f;
    for (int k = 0; k < 384; k++) a += s_tmp[k] * Wf[k * 128 + c];
    outg[r * 128 + c] = lrelu(a + bfv[c]);
}

// ---------------- persistent fused per-edge MLP (R4 block body + NT streams + XCD chunking) ----------------
// 256 blocks x 512 threads = 8 waves (2M x 4N). Each block owns a contiguous range of
// 128-edge tiles; ranges are XCD-chunked so each XCD covers a contiguous receiver super-range.
// Zero-reuse streams (edges reads, out_edges writes) are NON-TEMPORAL so the 640KB weight
// set stays L2/L3-resident across tiles (R7's 2.6GB weight re-fetch pathology).
__launch_bounds__(512, 2)
__global__ void edge_mlp_persist(const unsigned short* __restrict__ nodes_bf,
                                 const float* __restrict__ edges,
                                 const unsigned short* __restrict__ glbs_bf,
                                 const int* __restrict__ senders, const int* __restrict__ receivers,
                                 const int* __restrict__ sorted_eid,
                                 const int* __restrict__ n_edge, int G, int NT,
                                 const short* __restrict__ W0T, const short* __restrict__ W1T,
                                 const float* __restrict__ b0c, const float* __restrict__ b1c,
                                 float* __restrict__ out_nodes, float* __restrict__ out_edges) {
    __shared__ __align__(16) char sX[128 * 1024];
    __shared__ int s_eid[128], s_snd[128], s_recv[128], s_gid[128];

    const int tid  = threadIdx.x;
    const int lane = tid & 63;
    const int wid  = tid >> 6;
    const int wm   = wid >> 2;
    const int wn   = wid & 3;
    const int l15  = lane & 15;
    const int lk   = lane >> 4;

    // cumulative edge counts (graph id by ORIGINAL edge index), G <= 8
    int s_ = 0;
    int cu0 = 0x7fffffff, cu1 = 0x7fffffff, cu2 = 0x7fffffff, cu3 = 0x7fffffff;
    int cu4 = 0x7fffffff, cu5 = 0x7fffffff, cu6 = 0x7fffffff, cu7 = 0x7fffffff;
#define CUF(I, CU) if (I < G) { s_ += n_edge[I]; CU = s_; }
    CUF(0, cu0) CUF(1, cu1) CUF(2, cu2) CUF(3, cu3)
    CUF(4, cu4) CUF(5, cu5) CUF(6, cu6) CUF(7, cu7)
#undef CUF

    // XCD-chunked contiguous partition: blocks on the same XCD (bid%8) get adjacent chunks
    const int cid = (blockIdx.x & 7) * (GRID_P / 8) + (blockIdx.x >> 3);
    const int per = NT / GRID_P;
    const int rem = NT - per * GRID_P;
    const int t0  = cid * per + min(cid, rem);
    const int t1  = t0 + per + (cid < rem ? 1 : 0);

    for (int tile = t0; tile < t1; ++tile) {
        const int base = tile * 128;

        if (tid < 128) {
            int eid = sorted_eid[base + tid];
            s_eid[tid]  = eid;
            s_snd[tid]  = senders[eid];
            s_recv[tid] = receivers[eid];
            s_gid[tid]  = (eid >= cu0) + (eid >= cu1) + (eid >= cu2) + (eid >= cu3)
                        + (eid >= cu4) + (eid >= cu5) + (eid >= cu6) + (eid >= cu7);
        }
        __syncthreads();

        // ---- stage X into LDS ----
#pragma unroll
        for (int r = 0; r < 16; ++r) {
            const int e   = r * 8 + wid;    // wave-uniform row
            const int eid = s_eid[e];
            const int snd = s_snd[e];
            const int rcv = s_recv[e];
            const int g   = s_gid[e];
            char* dst = sX + e * 1024;      // linear dst; HW adds lane*16
            if (lk == 2) {
                // edges are f32, zero reuse: NON-TEMPORAL load + cvt + swizzled ds_write
                const float* fp = edges + (long)eid * 128 + l15 * 8;
                f32x4 v0 = __builtin_nontemporal_load((const f32x4*)fp);
                f32x4 v1 = __builtin_nontemporal_load((const f32x4*)(fp + 4));
                short8 a;
                a[0] = f2bf(v0[0]); a[1] = f2bf(v0[1]); a[2] = f2bf(v0[2]); a[3] = f2bf(v0[3]);
                a[4] = f2bf(v1[0]); a[5] = f2bf(v1[1]); a[6] = f2bf(v1[2]); a[7] = f2bf(v1[3]);
                *(short8*)(sX + e * 1024 + ((lane * 16) ^ ((e & 7) << 4))) = a;
            } else {
                // bf16 sources (reused, keep cached): glds, source pre-swizzled
                const int w = l15 ^ (e & 7);
                const unsigned short* bp = (lk == 0) ? nodes_bf + (long)snd * 128
                                         : (lk == 1) ? nodes_bf + (long)rcv * 128
                                                     : glbs_bf + (long)g * 128;
                __builtin_amdgcn_global_load_lds((g_u32*)(bp + w * 8), (l_u32*)dst, 16, 0, 0);
            }
        }
        __syncthreads();

        // ---- layer 1: X[128x512] @ W0c[512x512] ----
        f32x4 acc[4][8];
#pragma unroll
        for (int mt = 0; mt < 4; ++mt)
#pragma unroll
            for (int nt = 0; nt < 8; ++nt) acc[mt][nt] = (f32x4){0.f, 0.f, 0.f, 0.f};

#pragma unroll
        for (int t = 0; t < 16; ++t) {
            short8 bfr[8];
#pragma unroll
            for (int nt = 0; nt < 8; ++nt) {
                int n = wn * 128 + nt * 16 + l15;
                bfr[nt] = *(const short8*)(W0T + (long)n * 512 + t * 32 + lk * 8);
            }
#pragma unroll
            for (int mt = 0; mt < 4; ++mt) {
                int row = wm * 64 + mt * 16 + l15;
                short8 af = *(const short8*)(sX + row * 1024 + ((t * 64 + lk * 16) ^ ((row & 7) << 4)));
#pragma unroll
                for (int nt = 0; nt < 8; ++nt)
                    acc[mt][nt] = __builtin_amdgcn_mfma_f32_16x16x32_bf16(af, bfr[nt], acc[mt][nt], 0, 0, 0);
            }
        }
        __syncthreads();

        // bias + leaky + bf16 -> LDS H (same geometry/swizzle as X)
#pragma unroll
        for (int nt = 0; nt < 8; ++nt) {
            int col = wn * 128 + nt * 16 + l15;
            float bias = b0c[col];
#pragma unroll
            for (int mt = 0; mt < 4; ++mt) {
#pragma unroll
                for (int q = 0; q < 4; ++q) {
                    int row = wm * 64 + mt * 16 + lk * 4 + q;
                    float v = lrelu(acc[mt][nt][q] + bias);
                    *(short*)(sX + row * 1024 + ((col * 2) ^ ((row & 7) << 4))) = f2bf(v);
                }
            }
        }
        __syncthreads();

        // ---- layer 2 ----
        const int branch = wn >> 1;
        const int halfn  = wn & 1;
        f32x4 acc2[4][4];
#pragma unroll
        for (int mt = 0; mt < 4; ++mt)
#pragma unroll
            for (int nt = 0; nt < 4; ++nt) acc2[mt][nt] = (f32x4){0.f, 0.f, 0.f, 0.f};

#pragma unroll
        for (int kt = 0; kt < 8; ++kt) {
            short8 bfr2[4];
#pragma unroll
            for (int nt = 0; nt < 4; ++nt) {
                int ncl = halfn * 64 + nt * 16 + l15;
                bfr2[nt] = *(const short8*)(W1T + (long)(branch * 128 + ncl) * 256 + kt * 32 + lk * 8);
            }
#pragma unroll
            for (int mt = 0; mt < 4; ++mt) {
                int row = wm * 64 + mt * 16 + l15;
                int kbyte = (branch * 256 + kt * 32 + lk * 8) * 2;
                short8 af = *(const short8*)(sX + row * 1024 + (kbyte ^ ((row & 7) << 4)));
#pragma unroll
                for (int nt = 0; nt < 4; ++nt)
                    acc2[mt][nt] = __builtin_amdgcn_mfma_f32_16x16x32_bf16(af, bfr2[nt], acc2[mt][nt], 0, 0, 0);
            }
        }
        __syncthreads();  // H reads done; reuse sX as f32 msg buffer

        // epilogue: msgs -> LDS (swizzled), edge-updates -> global (NON-TEMPORAL, zero reuse)
#pragma unroll
        for (int nt = 0; nt < 4; ++nt) {
            int ncl = halfn * 64 + nt * 16 + l15;
            float bias = b1c[branch * 128 + ncl];
#pragma unroll
            for (int mt = 0; mt < 4; ++mt) {
#pragma unroll
                for (int q = 0; q < 4; ++q) {
                    int row = wm * 64 + mt * 16 + lk * 4 + q;
                    float v = lrelu(acc2[mt][nt][q] + bias);
                    if (branch == 0) {
                        *(float*)(sX + row * 512 + ((ncl * 4) ^ (((row >> 2) & 3) << 6))) = v;
                    } else {
                        __builtin_nontemporal_store(v, &out_edges[(long)s_eid[row] * D_ + ncl]);
                    }
                }
            }
        }
        __syncthreads();

        // segmented reduction over sorted receivers: one atomic per (segment x col)
        {
            int c  = tid & 127;
            int qr = tid >> 7;        // rows [qr*32, qr*32+32)
            int r0 = qr * 32, r1 = r0 + 32;
            float acc_s = 0.f;
            int cur = s_recv[r0];
            for (int r = r0; r < r1; ++r) {
                int rc = s_recv[r];
                if (rc != cur) {
                    atomicAdd(&out_nodes[(long)cur * D_ + c], acc_s);
                    acc_s = 0.f; cur = rc;
                }
                acc_s += *(const float*)(sX + r * 512 + ((c * 4) ^ (((r >> 2) & 3) << 6)));
            }
            atomicAdd(&out_nodes[(long)cur * D_ + c], acc_s);
        }
        __syncthreads();  // reduce reads done before next tile's meta/stage overwrite
    }
}

extern "C" void kernel_launch(void* const* d_in, const int* in_sizes, int n_in,
                              void* d_out, int out_size, void* d_ws, size_t ws_size,
                              hipStream_t stream) {
    const float* nodes     = (const float*)d_in[0];
    const float* edges     = (const float*)d_in[1];
    const float* glbs      = (const float*)d_in[2];
    const int*   senders   = (const int*)d_in[3];
    const int*   receivers = (const int*)d_in[4];
    const int*   n_node    = (const int*)d_in[5];
    const int*   n_edge    = (const int*)d_in[6];
    const float* Wn0 = (const float*)d_in[7];
    const float* bn0 = (const float*)d_in[8];
    const float* Wn1 = (const float*)d_in[9];
    const float* bn1 = (const float*)d_in[10];
    const float* We0 = (const float*)d_in[11];
    const float* be0 = (const float*)d_in[12];
    const float* We1 = (const float*)d_in[13];
    const float* be1 = (const float*)d_in[14];
    const float* Wgn = (const float*)d_in[15];
    const float* bgn = (const float*)d_in[16];
    const float* Wge = (const float*)d_in[17];
    const float* bge = (const float*)d_in[18];
    const float* Wg  = (const float*)d_in[19];
    const float* bg  = (const float*)d_in[20];
    const float* Wf  = (const float*)d_in[21];
    const float* bfv = (const float*)d_in[22];

    const int N = in_sizes[0] / 128;
    const int E = in_sizes[1] / 128;
    const int G = in_sizes[2] / 128;
    const int NT = E / 128;

    char*  ws   = (char*)d_ws;
    short* W0T  = (short*)(ws);                      // 524288 B
    short* W1T  = (short*)(ws + 524288);             // 131072 B
    float* b0c  = (float*)(ws + 655360);             // 2048 B
    float* b1c  = (float*)(ws + 657408);             // 1024 B
    float* sumn = (float*)(ws + 658432);             // 4096 B
    float* sume = (float*)(ws + 662528);             // 4096 B
    unsigned short* glbs_bf  = (unsigned short*)(ws + 666624);   // 2048 B
    unsigned short* nodes_bf = (unsigned short*)(ws + 669696);   // N*256 B
    char*  ws2  = ws + 669696 + (size_t)N * 256;
    int* cnt        = (int*)(ws2);                   // N*4
    int* tmp_off    = (int*)(ws2 + (size_t)N * 4);   // N*4
    int* sorted_eid = (int*)(ws2 + (size_t)N * 8);   // E*4

    float* out_nodes = (float*)d_out;
    float* out_edges = out_nodes + (long)N * 128;
    float* out_glb   = out_edges + (long)E * 128;

    hipMemsetAsync(out_nodes, 0, (size_t)N * 128 * sizeof(float), stream);
    hipMemsetAsync(sumn, 0, 8192, stream);
    hipMemsetAsync(cnt, 0, (size_t)N * 4, stream);

    const long nq = (long)N * 32;
    const long prep_items = nq + 512 * 512 + 256 * 256 + 768 + 1024;
    prep<<<(int)((prep_items + 255) / 256), 256, 0, stream>>>(
        Wn0, We0, Wn1, We1, bn0, be0, bn1, be1, nodes, glbs, nq,
        W0T, W1T, b0c, b1c, nodes_bf, glbs_bf);

    hist_recv<<<(E + 255) / 256, 256, 0, stream>>>(receivers, E, cnt);
    scan_counts<<<1, 256, 0, stream>>>(cnt, N, tmp_off);
    place_edges<<<(E + 255) / 256, 256, 0, stream>>>(receivers, E, tmp_off, sorted_eid);

    edge_mlp_persist<<<GRID_P, 512, 0, stream>>>(nodes_bf, edges, glbs_bf, senders, receivers,
                                                 sorted_eid, n_edge, G, NT,
                                                 W0T, W1T, b0c, b1c, out_nodes, out_edges);

    seg_sum<<<(N + 127) / 128, 256, 0, stream>>>(nodes, n_node, G, N, 128, sumn);
    seg_sum<<<(E + 255) / 256, 256, 0, stream>>>(edges, n_edge, G, E, 256, sume);

    global_mlp<<<G, 128, 0, stream>>>(glbs, sumn, sume, Wg, bg, Wgn, bgn, Wge, bge, Wf, bfv,
                                      out_glb);
}

// Round 9
// 2274.790 us; speedup vs baseline: 1.1217x; 1.1148x over previous
//
#include <hip/hip_runtime.h>
#include <hip/hip_bf16.h>

#define D_ 128

typedef __attribute__((ext_vector_type(8))) short short8;
typedef __attribute__((ext_vector_type(4))) float f32x4;
typedef __attribute__((address_space(1))) const unsigned int g_u32;
typedef __attribute__((address_space(3))) unsigned int l_u32;

static __device__ __forceinline__ float lrelu(float x) { return x > 0.f ? x : 0.01f * x; }
static __device__ __forceinline__ short f2bf(float f) {
    __hip_bfloat16 h = __float2bfloat16(f);
    return *reinterpret_cast<short*>(&h);
}
static __device__ __forceinline__ unsigned short f2bfu(float f) {
    __hip_bfloat16 h = __float2bfloat16(f);
    return *reinterpret_cast<unsigned short*>(&h);
}

// ---------------- prep: weights f32->bf16 transposed+combined, nodes/glbs -> bf16 ----------------
__global__ void prep(const float* __restrict__ Wn0, const float* __restrict__ We0,
                     const float* __restrict__ Wn1, const float* __restrict__ We1,
                     const float* __restrict__ bn0, const float* __restrict__ be0,
                     const float* __restrict__ bn1, const float* __restrict__ be1,
                     const float* __restrict__ nodes, const float* __restrict__ glbs,
                     long nq,
                     short* __restrict__ W0T, short* __restrict__ W1T,
                     float* __restrict__ b0c, float* __restrict__ b1c,
                     unsigned short* __restrict__ nodes_bf, unsigned short* __restrict__ glbs_bf) {
    long i = (long)blockIdx.x * 256 + threadIdx.x;
    if (i < nq) {
        float4 v = ((const float4*)nodes)[i];
        short4 o;
        o.x = f2bf(v.x); o.y = f2bf(v.y); o.z = f2bf(v.z); o.w = f2bf(v.w);
        ((short4*)nodes_bf)[i] = o;
        return;
    }
    long j = i - nq;
    if (j < 512 * 512) {
        int n = (int)(j >> 9), k = (int)(j & 511);
        float v = (n < 256) ? Wn0[k * 256 + n] : We0[k * 256 + (n - 256)];
        W0T[j] = f2bf(v);
        return;
    }
    j -= 512 * 512;
    if (j < 256 * 256) {
        int n = (int)(j >> 8), k = (int)(j & 255);
        float v = (n < 128) ? Wn1[k * 128 + n] : We1[k * 128 + (n - 128)];
        W1T[j] = f2bf(v);
        return;
    }
    j -= 256 * 256;
    if (j < 512) { b0c[j] = (j < 256) ? bn0[j] : be0[j - 256]; return; }
    if (j < 768) { int t = (int)j - 512; b1c[t] = (t < 128) ? bn1[t] : be1[t - 128]; return; }
    j -= 768;
    if (j < 1024) glbs_bf[j] = f2bfu(glbs[j]);
}

// ---------------- counting sort of edges by receiver ----------------
__global__ void hist_recv(const int* __restrict__ receivers, int E_, int* __restrict__ cnt) {
    int e = blockIdx.x * 256 + threadIdx.x;
    if (e < E_) atomicAdd(&cnt[receivers[e]], 1);
}

__global__ void scan_counts(const int* __restrict__ cnt, int N_, int* __restrict__ off) {
    __shared__ int part[256];
    int t = threadIdx.x;
    int chunk = (N_ + 255) / 256;
    int b = t * chunk, e = min(N_, b + chunk);
    int s = 0;
    for (int i = b; i < e; i++) s += cnt[i];
    part[t] = s;
    __syncthreads();
    for (int o = 1; o < 256; o <<= 1) {
        int v = (t >= o) ? part[t - o] : 0;
        __syncthreads();
        part[t] += v;
        __syncthreads();
    }
    int run = part[t] - s;
    for (int i = b; i < e; i++) { off[i] = run; run += cnt[i]; }
}

__global__ void place_edges(const int* __restrict__ receivers, int E_,
                            int* __restrict__ off, int* __restrict__ sorted) {
    int e = blockIdx.x * 256 + threadIdx.x;
    if (e < E_) {
        int p = atomicAdd(&off[receivers[e]], 1);
        sorted[p] = e;
    }
}

// ---------------- per-graph segment sums ----------------
__global__ void seg_sum(const float* __restrict__ src, const int* __restrict__ counts,
                        int G, int rows, int chunk, float* __restrict__ out) {
    int c4 = threadIdx.x & 31;
    int rl = threadIdx.x >> 5;
    int r0 = blockIdx.x * chunk + rl;
    int rend = min(rows, blockIdx.x * chunk + chunk);
    int s_ = 0;
    int cu0 = 0x7fffffff, cu1 = 0x7fffffff, cu2 = 0x7fffffff, cu3 = 0x7fffffff;
    int cu4 = 0x7fffffff, cu5 = 0x7fffffff, cu6 = 0x7fffffff, cu7 = 0x7fffffff;
#define CUF(I, CU) if (I < G) { s_ += counts[I]; CU = s_; }
    CUF(0, cu0) CUF(1, cu1) CUF(2, cu2) CUF(3, cu3)
    CUF(4, cu4) CUF(5, cu5) CUF(6, cu6) CUF(7, cu7)
#undef CUF
    f32x4 acc = {0.f, 0.f, 0.f, 0.f};
    int accg = -1;
    for (int r = r0; r < rend; r += 8) {
        int g = (r >= cu0) + (r >= cu1) + (r >= cu2) + (r >= cu3)
              + (r >= cu4) + (r >= cu5) + (r >= cu6) + (r >= cu7);
        if (g != accg) {
            if (accg >= 0) {
#pragma unroll
                for (int j = 0; j < 4; j++) atomicAdd(&out[accg * D_ + c4 * 4 + j], acc[j]);
            }
            acc = (f32x4){0.f, 0.f, 0.f, 0.f}; accg = g;
        }
        const float4 v = *(const float4*)(src + (long)r * D_ + c4 * 4);
        acc[0] += v.x; acc[1] += v.y; acc[2] += v.z; acc[3] += v.w;
    }
    if (accg >= 0) {
#pragma unroll
        for (int j = 0; j < 4; j++) atomicAdd(&out[accg * D_ + c4 * 4 + j], acc[j]);
    }
}

// ---------------- global-feature MLP ----------------
__global__ void global_mlp(const float* __restrict__ glbs, const float* __restrict__ sumn,
                           const float* __restrict__ sume,
                           const float* __restrict__ Wg, const float* __restrict__ bg,
                           const float* __restrict__ Wgn, const float* __restrict__ bgn,
                           const float* __restrict__ Wge, const float* __restrict__ bge,
                           const float* __restrict__ Wf, const float* __restrict__ bfv,
                           float* __restrict__ outg) {
    __shared__ float s_tmp[384];
    int r = blockIdx.x;
    int c = threadIdx.x;
    float a0 = 0.f, a1 = 0.f, a2 = 0.f;
    for (int k = 0; k < 128; k++) {
        a0 += glbs[r * 128 + k] * Wg[k * 128 + c];
        a1 += sumn[r * 128 + k] * Wgn[k * 128 + c];
        a2 += sume[r * 128 + k] * Wge[k * 128 + c];
    }
    s_tmp[c]       = lrelu(a0 + bg[c]);
    s_tmp[128 + c] = lrelu(a1 + bgn[c]);
    s_tmp[256 + c] = lrelu(a2 + bge[c]);
    __syncthreads();
    float a = 0.f;
    for (int k = 0; k < 384; k++) a += s_tmp[k] * Wf[k * 128 + c];
    outg[r * 128 + c] = lrelu(a + bfv[c]);
}

// ---------------- fused per-edge MLP, R4 body, TPB tiles per block (ablation) ----------------
// Dispatch mode. Block body byte-identical to R4; TPB = tiles processed sequentially per block.
// Three dispatches (TPB=1,2,4) over disjoint contiguous tile ranges measure launch/retire
// overhead vs intra-block latency.
template<int TPB>
__launch_bounds__(512, 2)
__global__ void edge_mlp(const unsigned short* __restrict__ nodes_bf,
                         const float* __restrict__ edges,
                         const unsigned short* __restrict__ glbs_bf,
                         const int* __restrict__ senders, const int* __restrict__ receivers,
                         const int* __restrict__ sorted_eid,
                         const int* __restrict__ n_edge, int G,
                         int tile0, int ntiles,
                         const short* __restrict__ W0T, const short* __restrict__ W1T,
                         const float* __restrict__ b0c, const float* __restrict__ b1c,
                         float* __restrict__ out_nodes, float* __restrict__ out_edges) {
    __shared__ __align__(16) char sX[128 * 1024];
    __shared__ int s_eid[128], s_snd[128], s_recv[128], s_gid[128];

    const int tid  = threadIdx.x;
    const int lane = tid & 63;
    const int wid  = tid >> 6;
    const int wm   = wid >> 2;
    const int wn   = wid & 3;
    const int l15  = lane & 15;
    const int lk   = lane >> 4;

    // cumulative edge counts (graph id by ORIGINAL edge index), G <= 8
    int s_ = 0;
    int cu0 = 0x7fffffff, cu1 = 0x7fffffff, cu2 = 0x7fffffff, cu3 = 0x7fffffff;
    int cu4 = 0x7fffffff, cu5 = 0x7fffffff, cu6 = 0x7fffffff, cu7 = 0x7fffffff;
#define CUF(I, CU) if (I < G) { s_ += n_edge[I]; CU = s_; }
    CUF(0, cu0) CUF(1, cu1) CUF(2, cu2) CUF(3, cu3)
    CUF(4, cu4) CUF(5, cu5) CUF(6, cu6) CUF(7, cu7)
#undef CUF

#pragma unroll 1
    for (int j = 0; j < TPB; ++j) {
        const int rel = blockIdx.x * TPB + j;
        if (rel >= ntiles) break;
        const int base = (tile0 + rel) * 128;

        if (tid < 128) {
            int eid = sorted_eid[base + tid];
            s_eid[tid]  = eid;
            s_snd[tid]  = senders[eid];
            s_recv[tid] = receivers[eid];
            s_gid[tid]  = (eid >= cu0) + (eid >= cu1) + (eid >= cu2) + (eid >= cu3)
                        + (eid >= cu4) + (eid >= cu5) + (eid >= cu6) + (eid >= cu7);
        }
        __syncthreads();

        // ---- stage X into LDS ----
#pragma unroll
        for (int r = 0; r < 16; ++r) {
            const int e   = r * 8 + wid;    // wave-uniform row
            const int eid = s_eid[e];
            const int snd = s_snd[e];
            const int rcv = s_recv[e];
            const int g   = s_gid[e];
            char* dst = sX + e * 1024;      // linear dst; HW adds lane*16
            if (lk == 2) {
                const float* fp = edges + (long)eid * 128 + l15 * 8;
                float4 v0 = *(const float4*)fp;
                float4 v1 = *(const float4*)(fp + 4);
                short8 a;
                a[0] = f2bf(v0.x); a[1] = f2bf(v0.y); a[2] = f2bf(v0.z); a[3] = f2bf(v0.w);
                a[4] = f2bf(v1.x); a[5] = f2bf(v1.y); a[6] = f2bf(v1.z); a[7] = f2bf(v1.w);
                *(short8*)(sX + e * 1024 + ((lane * 16) ^ ((e & 7) << 4))) = a;
            } else {
                const int w = l15 ^ (e & 7);
                const unsigned short* bp = (lk == 0) ? nodes_bf + (long)snd * 128
                                         : (lk == 1) ? nodes_bf + (long)rcv * 128
                                                     : glbs_bf + (long)g * 128;
                __builtin_amdgcn_global_load_lds((g_u32*)(bp + w * 8), (l_u32*)dst, 16, 0, 0);
            }
        }
        __syncthreads();

        // ---- layer 1: X[128x512] @ W0c[512x512] ----
        f32x4 acc[4][8];
#pragma unroll
        for (int mt = 0; mt < 4; ++mt)
#pragma unroll
            for (int nt = 0; nt < 8; ++nt) acc[mt][nt] = (f32x4){0.f, 0.f, 0.f, 0.f};

#pragma unroll
        for (int t = 0; t < 16; ++t) {
            short8 bfr[8];
#pragma unroll
            for (int nt = 0; nt < 8; ++nt) {
                int n = wn * 128 + nt * 16 + l15;
                bfr[nt] = *(const short8*)(W0T + (long)n * 512 + t * 32 + lk * 8);
            }
#pragma unroll
            for (int mt = 0; mt < 4; ++mt) {
                int row = wm * 64 + mt * 16 + l15;
                short8 af = *(const short8*)(sX + row * 1024 + ((t * 64 + lk * 16) ^ ((row & 7) << 4)));
#pragma unroll
                for (int nt = 0; nt < 8; ++nt)
                    acc[mt][nt] = __builtin_amdgcn_mfma_f32_16x16x32_bf16(af, bfr[nt], acc[mt][nt], 0, 0, 0);
            }
        }
        __syncthreads();

        // bias + leaky + bf16 -> LDS H (same geometry/swizzle as X)
#pragma unroll
        for (int nt = 0; nt < 8; ++nt) {
            int col = wn * 128 + nt * 16 + l15;
            float bias = b0c[col];
#pragma unroll
            for (int mt = 0; mt < 4; ++mt) {
#pragma unroll
                for (int q = 0; q < 4; ++q) {
                    int row = wm * 64 + mt * 16 + lk * 4 + q;
                    float v = lrelu(acc[mt][nt][q] + bias);
                    *(short*)(sX + row * 1024 + ((col * 2) ^ ((row & 7) << 4))) = f2bf(v);
                }
            }
        }
        __syncthreads();

        // ---- layer 2 ----
        const int branch = wn >> 1;
        const int halfn  = wn & 1;
        f32x4 acc2[4][4];
#pragma unroll
        for (int mt = 0; mt < 4; ++mt)
#pragma unroll
            for (int nt = 0; nt < 4; ++nt) acc2[mt][nt] = (f32x4){0.f, 0.f, 0.f, 0.f};

#pragma unroll
        for (int kt = 0; kt < 8; ++kt) {
            short8 bfr2[4];
#pragma unroll
            for (int nt = 0; nt < 4; ++nt) {
                int ncl = halfn * 64 + nt * 16 + l15;
                bfr2[nt] = *(const short8*)(W1T + (long)(branch * 128 + ncl) * 256 + kt * 32 + lk * 8);
            }
#pragma unroll
            for (int mt = 0; mt < 4; ++mt) {
                int row = wm * 64 + mt * 16 + l15;
                int kbyte = (branch * 256 + kt * 32 + lk * 8) * 2;
                short8 af = *(const short8*)(sX + row * 1024 + (kbyte ^ ((row & 7) << 4)));
#pragma unroll
                for (int nt = 0; nt < 4; ++nt)
                    acc2[mt][nt] = __builtin_amdgcn_mfma_f32_16x16x32_bf16(af, bfr2[nt], acc2[mt][nt], 0, 0, 0);
            }
        }
        __syncthreads();  // H reads done; reuse sX as f32 msg buffer

        // epilogue: msgs -> LDS (swizzled), edge-updates -> global
#pragma unroll
        for (int nt = 0; nt < 4; ++nt) {
            int ncl = halfn * 64 + nt * 16 + l15;
            float bias = b1c[branch * 128 + ncl];
#pragma unroll
            for (int mt = 0; mt < 4; ++mt) {
#pragma unroll
                for (int q = 0; q < 4; ++q) {
                    int row = wm * 64 + mt * 16 + lk * 4 + q;
                    float v = lrelu(acc2[mt][nt][q] + bias);
                    if (branch == 0) {
                        *(float*)(sX + row * 512 + ((ncl * 4) ^ (((row >> 2) & 3) << 6))) = v;
                    } else {
                        out_edges[(long)s_eid[row] * D_ + ncl] = v;
                    }
                }
            }
        }
        __syncthreads();

        // segmented reduction over sorted receivers: one atomic per (segment x col)
        {
            int c  = tid & 127;
            int qr = tid >> 7;        // rows [qr*32, qr*32+32)
            int r0 = qr * 32, r1 = r0 + 32;
            float acc_s = 0.f;
            int cur = s_recv[r0];
            for (int r = r0; r < r1; ++r) {
                int rc = s_recv[r];
                if (rc != cur) {
                    atomicAdd(&out_nodes[(long)cur * D_ + c], acc_s);
                    acc_s = 0.f; cur = rc;
                }
                acc_s += *(const float*)(sX + r * 512 + ((c * 4) ^ (((r >> 2) & 3) << 6)));
            }
            atomicAdd(&out_nodes[(long)cur * D_ + c], acc_s);
        }
        __syncthreads();  // reduce reads done before next tile's meta/stage overwrite
    }
}

extern "C" void kernel_launch(void* const* d_in, const int* in_sizes, int n_in,
                              void* d_out, int out_size, void* d_ws, size_t ws_size,
                              hipStream_t stream) {
    const float* nodes     = (const float*)d_in[0];
    const float* edges     = (const float*)d_in[1];
    const float* glbs      = (const float*)d_in[2];
    const int*   senders   = (const int*)d_in[3];
    const int*   receivers = (const int*)d_in[4];
    const int*   n_node    = (const int*)d_in[5];
    const int*   n_edge    = (const int*)d_in[6];
    const float* Wn0 = (const float*)d_in[7];
    const float* bn0 = (const float*)d_in[8];
    const float* Wn1 = (const float*)d_in[9];
    const float* bn1 = (const float*)d_in[10];
    const float* We0 = (const float*)d_in[11];
    const float* be0 = (const float*)d_in[12];
    const float* We1 = (const float*)d_in[13];
    const float* be1 = (const float*)d_in[14];
    const float* Wgn = (const float*)d_in[15];
    const float* bgn = (const float*)d_in[16];
    const float* Wge = (const float*)d_in[17];
    const float* bge = (const float*)d_in[18];
    const float* Wg  = (const float*)d_in[19];
    const float* bg  = (const float*)d_in[20];
    const float* Wf  = (const float*)d_in[21];
    const float* bfv = (const float*)d_in[22];

    const int N = in_sizes[0] / 128;
    const int E = in_sizes[1] / 128;
    const int G = in_sizes[2] / 128;
    const int NT = E / 128;   // 3125

    char*  ws   = (char*)d_ws;
    short* W0T  = (short*)(ws);                      // 524288 B
    short* W1T  = (short*)(ws + 524288);             // 131072 B
    float* b0c  = (float*)(ws + 655360);             // 2048 B
    float* b1c  = (float*)(ws + 657408);             // 1024 B
    float* sumn = (float*)(ws + 658432);             // 4096 B
    float* sume = (float*)(ws + 662528);             // 4096 B
    unsigned short* glbs_bf  = (unsigned short*)(ws + 666624);   // 2048 B
    unsigned short* nodes_bf = (unsigned short*)(ws + 669696);   // N*256 B
    char*  ws2  = ws + 669696 + (size_t)N * 256;
    int* cnt        = (int*)(ws2);                   // N*4
    int* tmp_off    = (int*)(ws2 + (size_t)N * 4);   // N*4
    int* sorted_eid = (int*)(ws2 + (size_t)N * 8);   // E*4

    float* out_nodes = (float*)d_out;
    float* out_edges = out_nodes + (long)N * 128;
    float* out_glb   = out_edges + (long)E * 128;

    hipMemsetAsync(out_nodes, 0, (size_t)N * 128 * sizeof(float), stream);
    hipMemsetAsync(sumn, 0, 8192, stream);
    hipMemsetAsync(cnt, 0, (size_t)N * 4, stream);

    const long nq = (long)N * 32;
    const long prep_items = nq + 512 * 512 + 256 * 256 + 768 + 1024;
    prep<<<(int)((prep_items + 255) / 256), 256, 0, stream>>>(
        Wn0, We0, Wn1, We1, bn0, be0, bn1, be1, nodes, glbs, nq,
        W0T, W1T, b0c, b1c, nodes_bf, glbs_bf);

    hist_recv<<<(E + 255) / 256, 256, 0, stream>>>(receivers, E, cnt);
    scan_counts<<<1, 256, 0, stream>>>(cnt, N, tmp_off);
    place_edges<<<(E + 255) / 256, 256, 0, stream>>>(receivers, E, tmp_off, sorted_eid);

    // ---- TPB ablation: three dispatches over disjoint contiguous tile ranges ----
    // D1: tiles [0, 1125) as 1125 blocks x 1 tile
    // D2: tiles [1125, 2125) as 500 blocks x 2 tiles
    // D3: tiles [2125, 3125) as 250 blocks x 4 tiles
    {
        const int n1 = 1125;
        const int n2 = 1000;
        const int n3 = NT - n1 - n2;  // 1000 for NT=3125
        edge_mlp<1><<<n1, 512, 0, stream>>>(nodes_bf, edges, glbs_bf, senders, receivers,
                                            sorted_eid, n_edge, G, 0, n1,
                                            W0T, W1T, b0c, b1c, out_nodes, out_edges);
        edge_mlp<2><<<(n2 + 1) / 2, 512, 0, stream>>>(nodes_bf, edges, glbs_bf, senders, receivers,
                                            sorted_eid, n_edge, G, n1, n2,
                                            W0T, W1T, b0c, b1c, out_nodes, out_edges);
        edge_mlp<4><<<(n3 + 3) / 4, 512, 0, stream>>>(nodes_bf, edges, glbs_bf, senders, receivers,
                                            sorted_eid, n_edge, G, n1 + n2, n3,
                                            W0T, W1T, b0c, b1c, out_nodes, out_edges);
    }

    seg_sum<<<(N + 127) / 128, 256, 0, stream>>>(nodes, n_node, G, N, 128, sumn);
    seg_sum<<<(E + 255) / 256, 256, 0, stream>>>(edges, n_edge, G, E, 256, sume);

    global_mlp<<<G, 128, 0, stream>>>(glbs, sumn, sume, Wg, bg, Wgn, bgn, Wge, bge, Wf, bfv,
                                      out_glb);
}

// Round 10
// 1062.650 us; speedup vs baseline: 2.4011x; 2.1407x over previous
//
#include <hip/hip_runtime.h>
#include <hip/hip_bf16.h>

#define D_ 128

typedef __attribute__((ext_vector_type(8))) short short8;
typedef __attribute__((ext_vector_type(4))) float f32x4;
typedef __attribute__((address_space(1))) const unsigned int g_u32;
typedef __attribute__((address_space(3))) unsigned int l_u32;

static __device__ __forceinline__ float lrelu(float x) { return x > 0.f ? x : 0.01f * x; }
static __device__ __forceinline__ short f2bf(float f) {
    __hip_bfloat16 h = __float2bfloat16(f);
    return *reinterpret_cast<short*>(&h);
}
static __device__ __forceinline__ unsigned short f2bfu(float f) {
    __hip_bfloat16 h = __float2bfloat16(f);
    return *reinterpret_cast<unsigned short*>(&h);
}

// ---------------- prep: weights f32->bf16 transposed+combined, nodes/glbs -> bf16 ----------------
__global__ void prep(const float* __restrict__ Wn0, const float* __restrict__ We0,
                     const float* __restrict__ Wn1, const float* __restrict__ We1,
                     const float* __restrict__ bn0, const float* __restrict__ be0,
                     const float* __restrict__ bn1, const float* __restrict__ be1,
                     const float* __restrict__ nodes, const float* __restrict__ glbs,
                     long nq,
                     short* __restrict__ W0T, short* __restrict__ W1T,
                     float* __restrict__ b0c, float* __restrict__ b1c,
                     unsigned short* __restrict__ nodes_bf, unsigned short* __restrict__ glbs_bf) {
    long i = (long)blockIdx.x * 256 + threadIdx.x;
    if (i < nq) {
        float4 v = ((const float4*)nodes)[i];
        short4 o;
        o.x = f2bf(v.x); o.y = f2bf(v.y); o.z = f2bf(v.z); o.w = f2bf(v.w);
        ((short4*)nodes_bf)[i] = o;
        return;
    }
    long j = i - nq;
    if (j < 512 * 512) {
        int n = (int)(j >> 9), k = (int)(j & 511);
        float v = (n < 256) ? Wn0[k * 256 + n] : We0[k * 256 + (n - 256)];
        W0T[j] = f2bf(v);
        return;
    }
    j -= 512 * 512;
    if (j < 256 * 256) {
        int n = (int)(j >> 8), k = (int)(j & 255);
        float v = (n < 128) ? Wn1[k * 128 + n] : We1[k * 128 + (n - 128)];
        W1T[j] = f2bf(v);
        return;
    }
    j -= 256 * 256;
    if (j < 512) { b0c[j] = (j < 256) ? bn0[j] : be0[j - 256]; return; }
    if (j < 768) { int t = (int)j - 512; b1c[t] = (t < 128) ? bn1[t] : be1[t - 128]; return; }
    j -= 768;
    if (j < 1024) glbs_bf[j] = f2bfu(glbs[j]);
}

// ---------------- counting sort of edges by receiver ----------------
__global__ void hist_recv(const int* __restrict__ receivers, int E_, int* __restrict__ cnt) {
    int e = blockIdx.x * 256 + threadIdx.x;
    if (e < E_) atomicAdd(&cnt[receivers[e]], 1);
}

__global__ void scan_counts(const int* __restrict__ cnt, int N_, int* __restrict__ off) {
    __shared__ int part[256];
    int t = threadIdx.x;
    int chunk = (N_ + 255) / 256;
    int b = t * chunk, e = min(N_, b + chunk);
    int s = 0;
    for (int i = b; i < e; i++) s += cnt[i];
    part[t] = s;
    __syncthreads();
    for (int o = 1; o < 256; o <<= 1) {
        int v = (t >= o) ? part[t - o] : 0;
        __syncthreads();
        part[t] += v;
        __syncthreads();
    }
    int run = part[t] - s;
    for (int i = b; i < e; i++) { off[i] = run; run += cnt[i]; }
}

__global__ void place_edges(const int* __restrict__ receivers, int E_,
                            int* __restrict__ off, int* __restrict__ sorted) {
    int e = blockIdx.x * 256 + threadIdx.x;
    if (e < E_) {
        int p = atomicAdd(&off[receivers[e]], 1);
        sorted[p] = e;
    }
}

// ---------------- per-graph node sums ----------------
__global__ void seg_sum(const float* __restrict__ src, const int* __restrict__ counts,
                        int G, int rows, int chunk, float* __restrict__ out) {
    int c4 = threadIdx.x & 31;
    int rl = threadIdx.x >> 5;
    int r0 = blockIdx.x * chunk + rl;
    int rend = min(rows, blockIdx.x * chunk + chunk);
    int s_ = 0;
    int cu0 = 0x7fffffff, cu1 = 0x7fffffff, cu2 = 0x7fffffff, cu3 = 0x7fffffff;
    int cu4 = 0x7fffffff, cu5 = 0x7fffffff, cu6 = 0x7fffffff, cu7 = 0x7fffffff;
#define CUF(I, CU) if (I < G) { s_ += counts[I]; CU = s_; }
    CUF(0, cu0) CUF(1, cu1) CUF(2, cu2) CUF(3, cu3)
    CUF(4, cu4) CUF(5, cu5) CUF(6, cu6) CUF(7, cu7)
#undef CUF
    f32x4 acc = {0.f, 0.f, 0.f, 0.f};
    int accg = -1;
    for (int r = r0; r < rend; r += 8) {
        int g = (r >= cu0) + (r >= cu1) + (r >= cu2) + (r >= cu3)
              + (r >= cu4) + (r >= cu5) + (r >= cu6) + (r >= cu7);
        if (g != accg) {
            if (accg >= 0) {
#pragma unroll
                for (int j = 0; j < 4; j++) atomicAdd(&out[accg * D_ + c4 * 4 + j], acc[j]);
            }
            acc = (f32x4){0.f, 0.f, 0.f, 0.f}; accg = g;
        }
        const float4 v = *(const float4*)(src + (long)r * D_ + c4 * 4);
        acc[0] += v.x; acc[1] += v.y; acc[2] += v.z; acc[3] += v.w;
    }
    if (accg >= 0) {
#pragma unroll
        for (int j = 0; j < 4; j++) atomicAdd(&out[accg * D_ + c4 * 4 + j], acc[j]);
    }
}

// ---------------- edges: f32 -> bf16 conversion FUSED with per-graph edge sums ----------------
__global__ void conv_sum_edges(const float* __restrict__ src, const int* __restrict__ counts,
                               int G, int rows, int chunk,
                               float* __restrict__ out, unsigned short* __restrict__ dst_bf) {
    int c4 = threadIdx.x & 31;   // float4 column 0..31
    int rl = threadIdx.x >> 5;   // row lane 0..7
    int r0 = blockIdx.x * chunk + rl;
    int rend = min(rows, blockIdx.x * chunk + chunk);
    int s_ = 0;
    int cu0 = 0x7fffffff, cu1 = 0x7fffffff, cu2 = 0x7fffffff, cu3 = 0x7fffffff;
    int cu4 = 0x7fffffff, cu5 = 0x7fffffff, cu6 = 0x7fffffff, cu7 = 0x7fffffff;
#define CUF(I, CU) if (I < G) { s_ += counts[I]; CU = s_; }
    CUF(0, cu0) CUF(1, cu1) CUF(2, cu2) CUF(3, cu3)
    CUF(4, cu4) CUF(5, cu5) CUF(6, cu6) CUF(7, cu7)
#undef CUF
    f32x4 acc = {0.f, 0.f, 0.f, 0.f};
    int accg = -1;
    for (int r = r0; r < rend; r += 8) {
        int g = (r >= cu0) + (r >= cu1) + (r >= cu2) + (r >= cu3)
              + (r >= cu4) + (r >= cu5) + (r >= cu6) + (r >= cu7);
        if (g != accg) {
            if (accg >= 0) {
#pragma unroll
                for (int j = 0; j < 4; j++) atomicAdd(&out[accg * D_ + c4 * 4 + j], acc[j]);
            }
            acc = (f32x4){0.f, 0.f, 0.f, 0.f}; accg = g;
        }
        const float4 v = *(const float4*)(src + (long)r * D_ + c4 * 4);
        acc[0] += v.x; acc[1] += v.y; acc[2] += v.z; acc[3] += v.w;
        short4 o;
        o.x = f2bf(v.x); o.y = f2bf(v.y); o.z = f2bf(v.z); o.w = f2bf(v.w);
        *(short4*)(dst_bf + (long)r * D_ + c4 * 4) = o;
    }
    if (accg >= 0) {
#pragma unroll
        for (int j = 0; j < 4; j++) atomicAdd(&out[accg * D_ + c4 * 4 + j], acc[j]);
    }
}

// ---------------- global-feature MLP ----------------
__global__ void global_mlp(const float* __restrict__ glbs, const float* __restrict__ sumn,
                           const float* __restrict__ sume,
                           const float* __restrict__ Wg, const float* __restrict__ bg,
                           const float* __restrict__ Wgn, const float* __restrict__ bgn,
                           const float* __restrict__ Wge, const float* __restrict__ bge,
                           const float* __restrict__ Wf, const float* __restrict__ bfv,
                           float* __restrict__ outg) {
    __shared__ float s_tmp[384];
    int r = blockIdx.x;
    int c = threadIdx.x;
    float a0 = 0.f, a1 = 0.f, a2 = 0.f;
    for (int k = 0; k < 128; k++) {
        a0 += glbs[r * 128 + k] * Wg[k * 128 + c];
        a1 += sumn[r * 128 + k] * Wgn[k * 128 + c];
        a2 += sume[r * 128 + k] * Wge[k * 128 + c];
    }
    s_tmp[c]       = lrelu(a0 + bg[c]);
    s_tmp[128 + c] = lrelu(a1 + bgn[c]);
    s_tmp[256 + c] = lrelu(a2 + bge[c]);
    __syncthreads();
    float a = 0.f;
    for (int k = 0; k < 384; k++) a += s_tmp[k] * Wf[k * 128 + c];
    outg[r * 128 + c] = lrelu(a + bfv[c]);
}

// ---------------- fused per-edge MLP (R4 regime: single dispatch, 1 tile/block) ----------------
// 3125 blocks x 512 threads = 8 waves (2M x 4N). XCD-chunked tile swizzle within each
// 256-block round. Stage is pure global_load_lds (all sources bf16).
__launch_bounds__(512, 2)
__global__ void edge_mlp(const unsigned short* __restrict__ nodes_bf,
                         const unsigned short* __restrict__ edges_bf,
                         const unsigned short* __restrict__ glbs_bf,
                         const int* __restrict__ senders, const int* __restrict__ receivers,
                         const int* __restrict__ sorted_eid,
                         const int* __restrict__ n_edge, int G, int NT,
                         const short* __restrict__ W0T, const short* __restrict__ W1T,
                         const float* __restrict__ b0c, const float* __restrict__ b1c,
                         float* __restrict__ out_nodes, float* __restrict__ out_edges) {
    __shared__ __align__(16) char sX[128 * 1024];
    __shared__ int s_eid[128], s_snd[128], s_recv[128], s_gid[128];

    const int tid  = threadIdx.x;
    const int lane = tid & 63;
    const int wid  = tid >> 6;
    const int wm   = wid >> 2;
    const int wn   = wid & 3;
    const int l15  = lane & 15;
    const int lk   = lane >> 4;

    // XCD-chunked swizzle within each 256-block round: same-XCD blocks take 32 consecutive tiles
    int tile;
    {
        const int span = blockIdx.x & ~255;
        if (span + 256 <= NT)
            tile = span + (((blockIdx.x & 7) << 5) | ((blockIdx.x & 255) >> 3));
        else
            tile = blockIdx.x;  // tail: identity
    }
    const int base = tile * 128;

    // cumulative edge counts (graph id by ORIGINAL edge index), G <= 8
    int s_ = 0;
    int cu0 = 0x7fffffff, cu1 = 0x7fffffff, cu2 = 0x7fffffff, cu3 = 0x7fffffff;
    int cu4 = 0x7fffffff, cu5 = 0x7fffffff, cu6 = 0x7fffffff, cu7 = 0x7fffffff;
#define CUF(I, CU) if (I < G) { s_ += n_edge[I]; CU = s_; }
    CUF(0, cu0) CUF(1, cu1) CUF(2, cu2) CUF(3, cu3)
    CUF(4, cu4) CUF(5, cu5) CUF(6, cu6) CUF(7, cu7)
#undef CUF

    if (tid < 128) {
        int eid = sorted_eid[base + tid];
        s_eid[tid]  = eid;
        s_snd[tid]  = senders[eid];
        s_recv[tid] = receivers[eid];
        s_gid[tid]  = (eid >= cu0) + (eid >= cu1) + (eid >= cu2) + (eid >= cu3)
                    + (eid >= cu4) + (eid >= cu5) + (eid >= cu6) + (eid >= cu7);
    }
    __syncthreads();

    // ---- stage X into LDS: pure glds, source pre-swizzled ----
#pragma unroll
    for (int r = 0; r < 16; ++r) {
        const int e = r * 8 + wid;      // wave-uniform row
        char* dst = sX + e * 1024;      // linear dst; HW adds lane*16
        const int w = l15 ^ (e & 7);
        const unsigned short* bp = (lk == 0) ? nodes_bf + (long)s_snd[e] * 128
                                 : (lk == 1) ? nodes_bf + (long)s_recv[e] * 128
                                 : (lk == 2) ? edges_bf + (long)s_eid[e] * 128
                                             : glbs_bf + (long)s_gid[e] * 128;
        __builtin_amdgcn_global_load_lds((g_u32*)(bp + w * 8), (l_u32*)dst, 16, 0, 0);
    }
    __syncthreads();

    // ---- layer 1: X[128x512] @ W0c[512x512] ----
    f32x4 acc[4][8];
#pragma unroll
    for (int mt = 0; mt < 4; ++mt)
#pragma unroll
        for (int nt = 0; nt < 8; ++nt) acc[mt][nt] = (f32x4){0.f, 0.f, 0.f, 0.f};

#pragma unroll
    for (int t = 0; t < 16; ++t) {
        short8 bfr[8];
#pragma unroll
        for (int nt = 0; nt < 8; ++nt) {
            int n = wn * 128 + nt * 16 + l15;
            bfr[nt] = *(const short8*)(W0T + (long)n * 512 + t * 32 + lk * 8);
        }
#pragma unroll
        for (int mt = 0; mt < 4; ++mt) {
            int row = wm * 64 + mt * 16 + l15;
            short8 af = *(const short8*)(sX + row * 1024 + ((t * 64 + lk * 16) ^ ((row & 7) << 4)));
#pragma unroll
            for (int nt = 0; nt < 8; ++nt)
                acc[mt][nt] = __builtin_amdgcn_mfma_f32_16x16x32_bf16(af, bfr[nt], acc[mt][nt], 0, 0, 0);
        }
    }
    __syncthreads();

    // bias + leaky + bf16 -> LDS H (same geometry/swizzle as X)
#pragma unroll
    for (int nt = 0; nt < 8; ++nt) {
        int col = wn * 128 + nt * 16 + l15;
        float bias = b0c[col];
#pragma unroll
        for (int mt = 0; mt < 4; ++mt) {
#pragma unroll
            for (int q = 0; q < 4; ++q) {
                int row = wm * 64 + mt * 16 + lk * 4 + q;
                float v = lrelu(acc[mt][nt][q] + bias);
                *(short*)(sX + row * 1024 + ((col * 2) ^ ((row & 7) << 4))) = f2bf(v);
            }
        }
    }
    __syncthreads();

    // ---- layer 2 ----
    const int branch = wn >> 1;
    const int halfn  = wn & 1;
    f32x4 acc2[4][4];
#pragma unroll
    for (int mt = 0; mt < 4; ++mt)
#pragma unroll
        for (int nt = 0; nt < 4; ++nt) acc2[mt][nt] = (f32x4){0.f, 0.f, 0.f, 0.f};

#pragma unroll
    for (int kt = 0; kt < 8; ++kt) {
        short8 bfr2[4];
#pragma unroll
        for (int nt = 0; nt < 4; ++nt) {
            int ncl = halfn * 64 + nt * 16 + l15;
            bfr2[nt] = *(const short8*)(W1T + (long)(branch * 128 + ncl) * 256 + kt * 32 + lk * 8);
        }
#pragma unroll
        for (int mt = 0; mt < 4; ++mt) {
            int row = wm * 64 + mt * 16 + l15;
            int kbyte = (branch * 256 + kt * 32 + lk * 8) * 2;
            short8 af = *(const short8*)(sX + row * 1024 + (kbyte ^ ((row & 7) << 4)));
#pragma unroll
            for (int nt = 0; nt < 4; ++nt)
                acc2[mt][nt] = __builtin_amdgcn_mfma_f32_16x16x32_bf16(af, bfr2[nt], acc2[mt][nt], 0, 0, 0);
        }
    }
    __syncthreads();  // H reads done; reuse sX as f32 msg buffer

    // epilogue: msgs -> LDS (swizzled), edge-updates -> global
#pragma unroll
    for (int nt = 0; nt < 4; ++nt) {
        int ncl = halfn * 64 + nt * 16 + l15;
        float bias = b1c[branch * 128 + ncl];
#pragma unroll
        for (int mt = 0; mt < 4; ++mt) {
#pragma unroll
            for (int q = 0; q < 4; ++q) {
                int row = wm * 64 + mt * 16 + lk * 4 + q;
                float v = lrelu(acc2[mt][nt][q] + bias);
                if (branch == 0) {
                    *(float*)(sX + row * 512 + ((ncl * 4) ^ (((row >> 2) & 3) << 6))) = v;
                } else {
                    out_edges[(long)s_eid[row] * D_ + ncl] = v;
                }
            }
        }
    }
    __syncthreads();

    // segmented reduction over sorted receivers: loads unrolled into registers first
    // (breaks the dependent load->branch->load chain), then register walk, one atomic
    // per (segment x col)
    {
        int c  = tid & 127;
        int qr = tid >> 7;        // rows [qr*32, qr*32+32)
        int r0 = qr * 32;
        float v[32];
#pragma unroll
        for (int i = 0; i < 32; ++i) {
            int r = r0 + i;
            v[i] = *(const float*)(sX + r * 512 + ((c * 4) ^ (((r >> 2) & 3) << 6)));
        }
        float acc_s = 0.f;
        int cur = s_recv[r0];
#pragma unroll
        for (int i = 0; i < 32; ++i) {
            int rc = s_recv[r0 + i];
            if (rc != cur) {
                atomicAdd(&out_nodes[(long)cur * D_ + c], acc_s);
                acc_s = 0.f; cur = rc;
            }
            acc_s += v[i];
        }
        atomicAdd(&out_nodes[(long)cur * D_ + c], acc_s);
    }
}

extern "C" void kernel_launch(void* const* d_in, const int* in_sizes, int n_in,
                              void* d_out, int out_size, void* d_ws, size_t ws_size,
                              hipStream_t stream) {
    const float* nodes     = (const float*)d_in[0];
    const float* edges     = (const float*)d_in[1];
    const float* glbs      = (const float*)d_in[2];
    const int*   senders   = (const int*)d_in[3];
    const int*   receivers = (const int*)d_in[4];
    const int*   n_node    = (const int*)d_in[5];
    const int*   n_edge    = (const int*)d_in[6];
    const float* Wn0 = (const float*)d_in[7];
    const float* bn0 = (const float*)d_in[8];
    const float* Wn1 = (const float*)d_in[9];
    const float* bn1 = (const float*)d_in[10];
    const float* We0 = (const float*)d_in[11];
    const float* be0 = (const float*)d_in[12];
    const float* We1 = (const float*)d_in[13];
    const float* be1 = (const float*)d_in[14];
    const float* Wgn = (const float*)d_in[15];
    const float* bgn = (const float*)d_in[16];
    const float* Wge = (const float*)d_in[17];
    const float* bge = (const float*)d_in[18];
    const float* Wg  = (const float*)d_in[19];
    const float* bg  = (const float*)d_in[20];
    const float* Wf  = (const float*)d_in[21];
    const float* bfv = (const float*)d_in[22];

    const int N = in_sizes[0] / 128;
    const int E = in_sizes[1] / 128;
    const int G = in_sizes[2] / 128;
    const int NT = E / 128;   // 3125

    char*  ws   = (char*)d_ws;
    short* W0T  = (short*)(ws);                      // 524288 B
    short* W1T  = (short*)(ws + 524288);             // 131072 B
    float* b0c  = (float*)(ws + 655360);             // 2048 B
    float* b1c  = (float*)(ws + 657408);             // 1024 B
    float* sumn = (float*)(ws + 658432);             // 4096 B
    float* sume = (float*)(ws + 662528);             // 4096 B
    unsigned short* glbs_bf  = (unsigned short*)(ws + 666624);   // 2048 B
    unsigned short* nodes_bf = (unsigned short*)(ws + 669696);   // N*256 B
    char*  ws2  = ws + 669696 + (size_t)N * 256;
    int* cnt        = (int*)(ws2);                   // N*4
    int* tmp_off    = (int*)(ws2 + (size_t)N * 4);   // N*4
    int* sorted_eid = (int*)(ws2 + (size_t)N * 8);   // E*4
    unsigned short* edges_bf = (unsigned short*)(ws2 + (size_t)N * 8 + (size_t)E * 4);  // E*256 B

    float* out_nodes = (float*)d_out;
    float* out_edges = out_nodes + (long)N * 128;
    float* out_glb   = out_edges + (long)E * 128;

    hipMemsetAsync(out_nodes, 0, (size_t)N * 128 * sizeof(float), stream);
    hipMemsetAsync(sumn, 0, 8192, stream);
    hipMemsetAsync(cnt, 0, (size_t)N * 4, stream);

    const long nq = (long)N * 32;
    const long prep_items = nq + 512 * 512 + 256 * 256 + 768 + 1024;
    prep<<<(int)((prep_items + 255) / 256), 256, 0, stream>>>(
        Wn0, We0, Wn1, We1, bn0, be0, bn1, be1, nodes, glbs, nq,
        W0T, W1T, b0c, b1c, nodes_bf, glbs_bf);

    hist_recv<<<(E + 255) / 256, 256, 0, stream>>>(receivers, E, cnt);
    scan_counts<<<1, 256, 0, stream>>>(cnt, N, tmp_off);
    place_edges<<<(E + 255) / 256, 256, 0, stream>>>(receivers, E, tmp_off, sorted_eid);

    // edges: f32->bf16 + per-graph sums (replaces seg_sum over edges); immediately before
    // edge_mlp so edges_bf is L2/L3-warm for the gather
    conv_sum_edges<<<(E + 511) / 512, 256, 0, stream>>>(edges, n_edge, G, E, 512, sume, edges_bf);

    edge_mlp<<<NT, 512, 0, stream>>>(nodes_bf, edges_bf, glbs_bf, senders, receivers,
                                     sorted_eid, n_edge, G, NT,
                                     W0T, W1T, b0c, b1c, out_nodes, out_edges);

    seg_sum<<<(N + 127) / 128, 256, 0, stream>>>(nodes, n_node, G, N, 128, sumn);

    global_mlp<<<G, 128, 0, stream>>>(glbs, sumn, sume, Wg, bg, Wgn, bgn, Wge, bge, Wf, bfv,
                                      out_glb);
}

// Round 11
// 998.863 us; speedup vs baseline: 2.5544x; 1.0639x over previous
//
#include <hip/hip_runtime.h>
#include <hip/hip_bf16.h>

#define D_ 128

typedef __attribute__((ext_vector_type(8))) short short8;
typedef __attribute__((ext_vector_type(4))) float f32x4;
typedef __attribute__((address_space(1))) const unsigned int g_u32;
typedef __attribute__((address_space(3))) unsigned int l_u32;

static __device__ __forceinline__ float lrelu(float x) { return x > 0.f ? x : 0.01f * x; }
static __device__ __forceinline__ short f2bf(float f) {
    __hip_bfloat16 h = __float2bfloat16(f);
    return *reinterpret_cast<short*>(&h);
}
static __device__ __forceinline__ unsigned short f2bfu(float f) {
    __hip_bfloat16 h = __float2bfloat16(f);
    return *reinterpret_cast<unsigned short*>(&h);
}

// ---------------- prep: weights f32->bf16 transposed+combined, nodes/glbs -> bf16 ----------------
__global__ void prep(const float* __restrict__ Wn0, const float* __restrict__ We0,
                     const float* __restrict__ Wn1, const float* __restrict__ We1,
                     const float* __restrict__ bn0, const float* __restrict__ be0,
                     const float* __restrict__ bn1, const float* __restrict__ be1,
                     const float* __restrict__ nodes, const float* __restrict__ glbs,
                     long nq,
                     short* __restrict__ W0T, short* __restrict__ W1T,
                     float* __restrict__ b0c, float* __restrict__ b1c,
                     unsigned short* __restrict__ nodes_bf, unsigned short* __restrict__ glbs_bf) {
    long i = (long)blockIdx.x * 256 + threadIdx.x;
    if (i < nq) {
        float4 v = ((const float4*)nodes)[i];
        short4 o;
        o.x = f2bf(v.x); o.y = f2bf(v.y); o.z = f2bf(v.z); o.w = f2bf(v.w);
        ((short4*)nodes_bf)[i] = o;
        return;
    }
    long j = i - nq;
    if (j < 512 * 512) {
        int n = (int)(j >> 9), k = (int)(j & 511);
        float v = (n < 256) ? Wn0[k * 256 + n] : We0[k * 256 + (n - 256)];
        W0T[j] = f2bf(v);
        return;
    }
    j -= 512 * 512;
    if (j < 256 * 256) {
        int n = (int)(j >> 8), k = (int)(j & 255);
        float v = (n < 128) ? Wn1[k * 128 + n] : We1[k * 128 + (n - 128)];
        W1T[j] = f2bf(v);
        return;
    }
    j -= 256 * 256;
    if (j < 512) { b0c[j] = (j < 256) ? bn0[j] : be0[j - 256]; return; }
    if (j < 768) { int t = (int)j - 512; b1c[t] = (t < 128) ? bn1[t] : be1[t - 128]; return; }
    j -= 768;
    if (j < 1024) glbs_bf[j] = f2bfu(glbs[j]);
}

// ---------------- counting sort of edges by receiver ----------------
__global__ void hist_recv(const int* __restrict__ receivers, int E_, int* __restrict__ cnt) {
    int e = blockIdx.x * 256 + threadIdx.x;
    if (e < E_) atomicAdd(&cnt[receivers[e]], 1);
}

__global__ void scan_counts(const int* __restrict__ cnt, int N_, int* __restrict__ off) {
    __shared__ int part[256];
    int t = threadIdx.x;
    int chunk = (N_ + 255) / 256;
    int b = t * chunk, e = min(N_, b + chunk);
    int s = 0;
    for (int i = b; i < e; i++) s += cnt[i];
    part[t] = s;
    __syncthreads();
    for (int o = 1; o < 256; o <<= 1) {
        int v = (t >= o) ? part[t - o] : 0;
        __syncthreads();
        part[t] += v;
        __syncthreads();
    }
    int run = part[t] - s;
    for (int i = b; i < e; i++) { off[i] = run; run += cnt[i]; }
}

__global__ void place_edges(const int* __restrict__ receivers, int E_,
                            int* __restrict__ off, int* __restrict__ sorted) {
    int e = blockIdx.x * 256 + threadIdx.x;
    if (e < E_) {
        int p = atomicAdd(&off[receivers[e]], 1);
        sorted[p] = e;
    }
}

// ---------------- per-graph node sums ----------------
__global__ void seg_sum(const float* __restrict__ src, const int* __restrict__ counts,
                        int G, int rows, int chunk, float* __restrict__ out) {
    int c4 = threadIdx.x & 31;
    int rl = threadIdx.x >> 5;
    int r0 = blockIdx.x * chunk + rl;
    int rend = min(rows, blockIdx.x * chunk + chunk);
    int s_ = 0;
    int cu0 = 0x7fffffff, cu1 = 0x7fffffff, cu2 = 0x7fffffff, cu3 = 0x7fffffff;
    int cu4 = 0x7fffffff, cu5 = 0x7fffffff, cu6 = 0x7fffffff, cu7 = 0x7fffffff;
#define CUF(I, CU) if (I < G) { s_ += counts[I]; CU = s_; }
    CUF(0, cu0) CUF(1, cu1) CUF(2, cu2) CUF(3, cu3)
    CUF(4, cu4) CUF(5, cu5) CUF(6, cu6) CUF(7, cu7)
#undef CUF
    f32x4 acc = {0.f, 0.f, 0.f, 0.f};
    int accg = -1;
    for (int r = r0; r < rend; r += 8) {
        int g = (r >= cu0) + (r >= cu1) + (r >= cu2) + (r >= cu3)
              + (r >= cu4) + (r >= cu5) + (r >= cu6) + (r >= cu7);
        if (g != accg) {
            if (accg >= 0) {
#pragma unroll
                for (int j = 0; j < 4; j++) atomicAdd(&out[accg * D_ + c4 * 4 + j], acc[j]);
            }
            acc = (f32x4){0.f, 0.f, 0.f, 0.f}; accg = g;
        }
        const float4 v = *(const float4*)(src + (long)r * D_ + c4 * 4);
        acc[0] += v.x; acc[1] += v.y; acc[2] += v.z; acc[3] += v.w;
    }
    if (accg >= 0) {
#pragma unroll
        for (int j = 0; j < 4; j++) atomicAdd(&out[accg * D_ + c4 * 4 + j], acc[j]);
    }
}

// ---------------- edges: f32 -> bf16 conversion FUSED with per-graph edge sums ----------------
__global__ void conv_sum_edges(const float* __restrict__ src, const int* __restrict__ counts,
                               int G, int rows, int chunk,
                               float* __restrict__ out, unsigned short* __restrict__ dst_bf) {
    int c4 = threadIdx.x & 31;
    int rl = threadIdx.x >> 5;
    int r0 = blockIdx.x * chunk + rl;
    int rend = min(rows, blockIdx.x * chunk + chunk);
    int s_ = 0;
    int cu0 = 0x7fffffff, cu1 = 0x7fffffff, cu2 = 0x7fffffff, cu3 = 0x7fffffff;
    int cu4 = 0x7fffffff, cu5 = 0x7fffffff, cu6 = 0x7fffffff, cu7 = 0x7fffffff;
#define CUF(I, CU) if (I < G) { s_ += counts[I]; CU = s_; }
    CUF(0, cu0) CUF(1, cu1) CUF(2, cu2) CUF(3, cu3)
    CUF(4, cu4) CUF(5, cu5) CUF(6, cu6) CUF(7, cu7)
#undef CUF
    f32x4 acc = {0.f, 0.f, 0.f, 0.f};
    int accg = -1;
    for (int r = r0; r < rend; r += 8) {
        int g = (r >= cu0) + (r >= cu1) + (r >= cu2) + (r >= cu3)
              + (r >= cu4) + (r >= cu5) + (r >= cu6) + (r >= cu7);
        if (g != accg) {
            if (accg >= 0) {
#pragma unroll
                for (int j = 0; j < 4; j++) atomicAdd(&out[accg * D_ + c4 * 4 + j], acc[j]);
            }
            acc = (f32x4){0.f, 0.f, 0.f, 0.f}; accg = g;
        }
        const float4 v = *(const float4*)(src + (long)r * D_ + c4 * 4);
        acc[0] += v.x; acc[1] += v.y; acc[2] += v.z; acc[3] += v.w;
        short4 o;
        o.x = f2bf(v.x); o.y = f2bf(v.y); o.z = f2bf(v.z); o.w = f2bf(v.w);
        *(short4*)(dst_bf + (long)r * D_ + c4 * 4) = o;
    }
    if (accg >= 0) {
#pragma unroll
        for (int j = 0; j < 4; j++) atomicAdd(&out[accg * D_ + c4 * 4 + j], acc[j]);
    }
}

// ---------------- global-feature MLP ----------------
__global__ void global_mlp(const float* __restrict__ glbs, const float* __restrict__ sumn,
                           const float* __restrict__ sume,
                           const float* __restrict__ Wg, const float* __restrict__ bg,
                           const float* __restrict__ Wgn, const float* __restrict__ bgn,
                           const float* __restrict__ Wge, const float* __restrict__ bge,
                           const float* __restrict__ Wf, const float* __restrict__ bfv,
                           float* __restrict__ outg) {
    __shared__ float s_tmp[384];
    int r = blockIdx.x;
    int c = threadIdx.x;
    float a0 = 0.f, a1 = 0.f, a2 = 0.f;
    for (int k = 0; k < 128; k++) {
        a0 += glbs[r * 128 + k] * Wg[k * 128 + c];
        a1 += sumn[r * 128 + k] * Wgn[k * 128 + c];
        a2 += sume[r * 128 + k] * Wge[k * 128 + c];
    }
    s_tmp[c]       = lrelu(a0 + bg[c]);
    s_tmp[128 + c] = lrelu(a1 + bgn[c]);
    s_tmp[256 + c] = lrelu(a2 + bge[c]);
    __syncthreads();
    float a = 0.f;
    for (int k = 0; k < 384; k++) a += s_tmp[k] * Wf[k * 128 + c];
    outg[r * 128 + c] = lrelu(a + bfv[c]);
}

// ---------------- fused per-edge MLP: 1024 threads = 16 waves (2M x 8N), 1 tile/block ----------------
// Same 128-edge tile, same LDS, same weight traffic as R10 — only wave count doubled
// (4 waves/SIMD instead of 2) for latency hiding.
__launch_bounds__(1024, 1)
__global__ void edge_mlp(const unsigned short* __restrict__ nodes_bf,
                         const unsigned short* __restrict__ edges_bf,
                         const unsigned short* __restrict__ glbs_bf,
                         const int* __restrict__ senders, const int* __restrict__ receivers,
                         const int* __restrict__ sorted_eid,
                         const int* __restrict__ n_edge, int G, int NT,
                         const short* __restrict__ W0T, const short* __restrict__ W1T,
                         const float* __restrict__ b0c, const float* __restrict__ b1c,
                         float* __restrict__ out_nodes, float* __restrict__ out_edges) {
    __shared__ __align__(16) char sX[128 * 1024];
    __shared__ int s_eid[128], s_snd[128], s_recv[128], s_gid[128];

    const int tid  = threadIdx.x;
    const int lane = tid & 63;
    const int wid  = tid >> 6;   // 0..15
    const int wm   = wid >> 3;   // 0..1 : 64-row slice
    const int wn   = wid & 7;    // 0..7 : 64-col slice (layer1)
    const int l15  = lane & 15;
    const int lk   = lane >> 4;

    // XCD-chunked swizzle within each 256-block round
    int tile;
    {
        const int span = blockIdx.x & ~255;
        if (span + 256 <= NT)
            tile = span + (((blockIdx.x & 7) << 5) | ((blockIdx.x & 255) >> 3));
        else
            tile = blockIdx.x;  // tail: identity
    }
    const int base = tile * 128;

    // cumulative edge counts (graph id by ORIGINAL edge index), G <= 8
    int s_ = 0;
    int cu0 = 0x7fffffff, cu1 = 0x7fffffff, cu2 = 0x7fffffff, cu3 = 0x7fffffff;
    int cu4 = 0x7fffffff, cu5 = 0x7fffffff, cu6 = 0x7fffffff, cu7 = 0x7fffffff;
#define CUF(I, CU) if (I < G) { s_ += n_edge[I]; CU = s_; }
    CUF(0, cu0) CUF(1, cu1) CUF(2, cu2) CUF(3, cu3)
    CUF(4, cu4) CUF(5, cu5) CUF(6, cu6) CUF(7, cu7)
#undef CUF

    if (tid < 128) {
        int eid = sorted_eid[base + tid];
        s_eid[tid]  = eid;
        s_snd[tid]  = senders[eid];
        s_recv[tid] = receivers[eid];
        s_gid[tid]  = (eid >= cu0) + (eid >= cu1) + (eid >= cu2) + (eid >= cu3)
                    + (eid >= cu4) + (eid >= cu5) + (eid >= cu6) + (eid >= cu7);
    }
    __syncthreads();

    // ---- stage X into LDS: pure glds, source pre-swizzled; 16 waves x 8 rows ----
#pragma unroll
    for (int r = 0; r < 8; ++r) {
        const int e = r * 16 + wid;     // wave-uniform row
        char* dst = sX + e * 1024;      // linear dst; HW adds lane*16
        const int w = l15 ^ (e & 7);
        const unsigned short* bp = (lk == 0) ? nodes_bf + (long)s_snd[e] * 128
                                 : (lk == 1) ? nodes_bf + (long)s_recv[e] * 128
                                 : (lk == 2) ? edges_bf + (long)s_eid[e] * 128
                                             : glbs_bf + (long)s_gid[e] * 128;
        __builtin_amdgcn_global_load_lds((g_u32*)(bp + w * 8), (l_u32*)dst, 16, 0, 0);
    }
    __syncthreads();

    // ---- layer 1: X[128x512] @ W0c[512x512]; wave = 64 rows x 64 cols ----
    f32x4 acc[4][4];
#pragma unroll
    for (int mt = 0; mt < 4; ++mt)
#pragma unroll
        for (int nt = 0; nt < 4; ++nt) acc[mt][nt] = (f32x4){0.f, 0.f, 0.f, 0.f};

#pragma unroll
    for (int t = 0; t < 16; ++t) {
        short8 bfr[4];
#pragma unroll
        for (int nt = 0; nt < 4; ++nt) {
            int n = wn * 64 + nt * 16 + l15;
            bfr[nt] = *(const short8*)(W0T + (long)n * 512 + t * 32 + lk * 8);
        }
#pragma unroll
        for (int mt = 0; mt < 4; ++mt) {
            int row = wm * 64 + mt * 16 + l15;
            short8 af = *(const short8*)(sX + row * 1024 + ((t * 64 + lk * 16) ^ ((row & 7) << 4)));
#pragma unroll
            for (int nt = 0; nt < 4; ++nt)
                acc[mt][nt] = __builtin_amdgcn_mfma_f32_16x16x32_bf16(af, bfr[nt], acc[mt][nt], 0, 0, 0);
        }
    }
    __syncthreads();

    // bias + leaky + bf16 -> LDS H (same geometry/swizzle as X)
#pragma unroll
    for (int nt = 0; nt < 4; ++nt) {
        int col = wn * 64 + nt * 16 + l15;
        float bias = b0c[col];
#pragma unroll
        for (int mt = 0; mt < 4; ++mt) {
#pragma unroll
            for (int q = 0; q < 4; ++q) {
                int row = wm * 64 + mt * 16 + lk * 4 + q;
                float v = lrelu(acc[mt][nt][q] + bias);
                *(short*)(sX + row * 1024 + ((col * 2) ^ ((row & 7) << 4))) = f2bf(v);
            }
        }
    }
    __syncthreads();

    // ---- layer 2: waves wn 0-3 node-msg, wn 4-7 edge-update; 32 cols each ----
    const int branch = wn >> 2;
    const int qn     = wn & 3;
    f32x4 acc2[4][2];
#pragma unroll
    for (int mt = 0; mt < 4; ++mt)
#pragma unroll
        for (int nt = 0; nt < 2; ++nt) acc2[mt][nt] = (f32x4){0.f, 0.f, 0.f, 0.f};

#pragma unroll
    for (int kt = 0; kt < 8; ++kt) {
        short8 bfr2[2];
#pragma unroll
        for (int nt = 0; nt < 2; ++nt) {
            int ncl = qn * 32 + nt * 16 + l15;
            bfr2[nt] = *(const short8*)(W1T + (long)(branch * 128 + ncl) * 256 + kt * 32 + lk * 8);
        }
#pragma unroll
        for (int mt = 0; mt < 4; ++mt) {
            int row = wm * 64 + mt * 16 + l15;
            int kbyte = (branch * 256 + kt * 32 + lk * 8) * 2;
            short8 af = *(const short8*)(sX + row * 1024 + (kbyte ^ ((row & 7) << 4)));
#pragma unroll
            for (int nt = 0; nt < 2; ++nt)
                acc2[mt][nt] = __builtin_amdgcn_mfma_f32_16x16x32_bf16(af, bfr2[nt], acc2[mt][nt], 0, 0, 0);
        }
    }
    __syncthreads();  // H reads done; reuse sX as f32 msg buffer

    // epilogue: msgs -> LDS (swizzled), edge-updates -> global
#pragma unroll
    for (int nt = 0; nt < 2; ++nt) {
        int ncl = qn * 32 + nt * 16 + l15;
        float bias = b1c[branch * 128 + ncl];
#pragma unroll
        for (int mt = 0; mt < 4; ++mt) {
#pragma unroll
            for (int q = 0; q < 4; ++q) {
                int row = wm * 64 + mt * 16 + lk * 4 + q;
                float v = lrelu(acc2[mt][nt][q] + bias);
                if (branch == 0) {
                    *(float*)(sX + row * 512 + ((ncl * 4) ^ (((row >> 2) & 3) << 6))) = v;
                } else {
                    out_edges[(long)s_eid[row] * D_ + ncl] = v;
                }
            }
        }
    }
    __syncthreads();

    // segmented reduction over sorted receivers: 1024 threads -> 8 row-groups of 16
    {
        int c  = tid & 127;
        int qr = tid >> 7;        // 0..7 -> rows [qr*16, qr*16+16)
        int r0 = qr * 16;
        float v[16];
#pragma unroll
        for (int i = 0; i < 16; ++i) {
            int r = r0 + i;
            v[i] = *(const float*)(sX + r * 512 + ((c * 4) ^ (((r >> 2) & 3) << 6)));
        }
        float acc_s = 0.f;
        int cur = s_recv[r0];
#pragma unroll
        for (int i = 0; i < 16; ++i) {
            int rc = s_recv[r0 + i];
            if (rc != cur) {
                atomicAdd(&out_nodes[(long)cur * D_ + c], acc_s);
                acc_s = 0.f; cur = rc;
            }
            acc_s += v[i];
        }
        atomicAdd(&out_nodes[(long)cur * D_ + c], acc_s);
    }
}

extern "C" void kernel_launch(void* const* d_in, const int* in_sizes, int n_in,
                              void* d_out, int out_size, void* d_ws, size_t ws_size,
                              hipStream_t stream) {
    const float* nodes     = (const float*)d_in[0];
    const float* edges     = (const float*)d_in[1];
    const float* glbs      = (const float*)d_in[2];
    const int*   senders   = (const int*)d_in[3];
    const int*   receivers = (const int*)d_in[4];
    const int*   n_node    = (const int*)d_in[5];
    const int*   n_edge    = (const int*)d_in[6];
    const float* Wn0 = (const float*)d_in[7];
    const float* bn0 = (const float*)d_in[8];
    const float* Wn1 = (const float*)d_in[9];
    const float* bn1 = (const float*)d_in[10];
    const float* We0 = (const float*)d_in[11];
    const float* be0 = (const float*)d_in[12];
    const float* We1 = (const float*)d_in[13];
    const float* be1 = (const float*)d_in[14];
    const float* Wgn = (const float*)d_in[15];
    const float* bgn = (const float*)d_in[16];
    const float* Wge = (const float*)d_in[17];
    const float* bge = (const float*)d_in[18];
    const float* Wg  = (const float*)d_in[19];
    const float* bg  = (const float*)d_in[20];
    const float* Wf  = (const float*)d_in[21];
    const float* bfv = (const float*)d_in[22];

    const int N = in_sizes[0] / 128;
    const int E = in_sizes[1] / 128;
    const int G = in_sizes[2] / 128;
    const int NT = E / 128;   // 3125

    char*  ws   = (char*)d_ws;
    short* W0T  = (short*)(ws);                      // 524288 B
    short* W1T  = (short*)(ws + 524288);             // 131072 B
    float* b0c  = (float*)(ws + 655360);             // 2048 B
    float* b1c  = (float*)(ws + 657408);             // 1024 B
    float* sumn = (float*)(ws + 658432);             // 4096 B
    float* sume = (float*)(ws + 662528);             // 4096 B
    unsigned short* glbs_bf  = (unsigned short*)(ws + 666624);   // 2048 B
    unsigned short* nodes_bf = (unsigned short*)(ws + 669696);   // N*256 B
    char*  ws2  = ws + 669696 + (size_t)N * 256;
    int* cnt        = (int*)(ws2);                   // N*4
    int* tmp_off    = (int*)(ws2 + (size_t)N * 4);   // N*4
    int* sorted_eid = (int*)(ws2 + (size_t)N * 8);   // E*4
    unsigned short* edges_bf = (unsigned short*)(ws2 + (size_t)N * 8 + (size_t)E * 4);  // E*256 B

    float* out_nodes = (float*)d_out;
    float* out_edges = out_nodes + (long)N * 128;
    float* out_glb   = out_edges + (long)E * 128;

    hipMemsetAsync(out_nodes, 0, (size_t)N * 128 * sizeof(float), stream);
    hipMemsetAsync(sumn, 0, 8192, stream);
    hipMemsetAsync(cnt, 0, (size_t)N * 4, stream);

    const long nq = (long)N * 32;
    const long prep_items = nq + 512 * 512 + 256 * 256 + 768 + 1024;
    prep<<<(int)((prep_items + 255) / 256), 256, 0, stream>>>(
        Wn0, We0, Wn1, We1, bn0, be0, bn1, be1, nodes, glbs, nq,
        W0T, W1T, b0c, b1c, nodes_bf, glbs_bf);

    hist_recv<<<(E + 255) / 256, 256, 0, stream>>>(receivers, E, cnt);
    scan_counts<<<1, 256, 0, stream>>>(cnt, N, tmp_off);
    place_edges<<<(E + 255) / 256, 256, 0, stream>>>(receivers, E, tmp_off, sorted_eid);

    conv_sum_edges<<<(E + 511) / 512, 256, 0, stream>>>(edges, n_edge, G, E, 512, sume, edges_bf);

    edge_mlp<<<NT, 1024, 0, stream>>>(nodes_bf, edges_bf, glbs_bf, senders, receivers,
                                      sorted_eid, n_edge, G, NT,
                                      W0T, W1T, b0c, b1c, out_nodes, out_edges);

    seg_sum<<<(N + 127) / 128, 256, 0, stream>>>(nodes, n_node, G, N, 128, sumn);

    global_mlp<<<G, 128, 0, stream>>>(glbs, sumn, sume, Wg, bg, Wgn, bgn, Wge, bge, Wf, bfv,
                                      out_glb);
}